// Round 8
// baseline (1537.199 us; speedup 1.0000x reference)
//
#include <hip/hip_runtime.h>
#include <hip/hip_bf16.h>
#include <math.h>

// Problem constants
#define Bn   64
#define Ssz  512     // W*H = 64*8
#define Ed   192
#define NHd  6
#define HDd  32
#define Ld   6
#define COd  256
#define Himg 8
#define Wimg 64
#define Mrows (Bn*Ssz)   // 32768

typedef unsigned int  uint;
typedef unsigned short ushort;
using short8 = __attribute__((ext_vector_type(8))) short;
using f32x4  = __attribute__((ext_vector_type(4))) float;

__device__ inline ushort f2b(float f) {          // fp32 -> bf16 RNE
    uint u = __builtin_bit_cast(uint, f);
    u = (u + 0x7FFFu + ((u >> 16) & 1u)) >> 16;
    return (ushort)u;
}

__device__ __forceinline__ float fexp2(float x) {
#if __has_builtin(__builtin_amdgcn_exp2f)
    return __builtin_amdgcn_exp2f(x);
#else
    return exp2f(x);
#endif
}

// packed f32x2 -> bf16x2 (lo = a, hi = b); no builtin on gfx950, inline asm
__device__ __forceinline__ uint cvt_pk_bf16(float a, float b) {
    uint r;
    asm("v_cvt_pk_bf16_f32 %0, %1, %2" : "=v"(r) : "v"(a), "v"(b));
    return r;
}

// async global->LDS 16B: lane i lands at lds + i*16 (wave-uniform lds base)
__device__ __forceinline__ void gload16(const ushort* g, ushort* l, int lane) {
#if __has_builtin(__builtin_amdgcn_global_load_lds)
    __builtin_amdgcn_global_load_lds(
        (const __attribute__((address_space(1))) uint*)g,
        (__attribute__((address_space(3))) uint*)l, 16, 0, 0);
#else
    *(uint4*)(l + (size_t)lane * 8) = *(const uint4*)g;
#endif
}

// ---------------------------------------------------------------------------
// ALL weight conversions in one dispatch:
//   [0, 663552)        in_w   -> Wb
//   [663552, 884736)   out_w
//   [884736, 1769472)  w1
//   [1769472, 2654208) w2  (k-columns kappa-permuted: k ^= 12 when bit2^bit3,
//                           matching fused_mlp's register-transposed H slots)
//   [2654208, 2801664) conv_w (transposed to [co][kh*192+c])
__global__ __launch_bounds__(256) void cvt_weights(const float* __restrict__ in_w,
                                                   const float* __restrict__ out_w,
                                                   const float* __restrict__ w1,
                                                   const float* __restrict__ w2,
                                                   const float* __restrict__ convw,
                                                   ushort* __restrict__ Wb) {
    int t = blockIdx.x * 256 + threadIdx.x;
    if (t >= 2801664) return;
    float v;
    if (t < 663552)        v = in_w[t];
    else if (t < 884736)   v = out_w[t - 663552];
    else if (t < 1769472)  v = w1[t - 884736];
    else if (t < 2654208) {
        int u = t - 1769472;
        int k = u % 768;
        int ks = k ^ ((((k >> 2) ^ (k >> 3)) & 1) * 12);
        v = w2[u - k + ks];
    } else {
        int u = t - 2654208;
        int co = u / 576, rem = u % 576;
        int kh = rem / Ed, c = rem % Ed;
        v = convw[((size_t)co * Ed + c) * 3 + kh];
    }
    Wb[t] = f2b(v);
}

// ---------------------------------------------------------------------------
// FUSED reshape + layer-0 LN1: image [B,E,8,64] -> LN over E at rows
// s = w*8 + h -> F1 fp32 + XNb bf16.
__global__ __launch_bounds__(256) void reshape_ln(const float* __restrict__ img,
                                                  const float* __restrict__ g,
                                                  const float* __restrict__ bb,
                                                  float* __restrict__ outf,
                                                  ushort* __restrict__ outb) {
    __shared__ float lds[Ed * 65];               // 49920 B
    const int b = blockIdx.x >> 3, h = blockIdx.x & 7;
    const int tid = threadIdx.x;
    const float* src = img + ((size_t)b * Ed * Himg + h) * Wimg;  // +c*512+w
    #pragma unroll
    for (int i = 0; i < 48; ++i) {
        int idx = i * 256 + tid;
        int c = idx >> 6, w = idx & 63;
        lds[c * 65 + w] = src[(size_t)c * 512 + w];
    }
    __syncthreads();

    const int w = tid >> 2, q = tid & 3;         // 4 lanes per row w
    float vals[48];
    float s = 0.f;
    #pragma unroll
    for (int j = 0; j < 48; ++j) {
        vals[j] = lds[(q * 48 + j) * 65 + w];
        s += vals[j];
    }
    s += __shfl_xor(s, 1); s += __shfl_xor(s, 2);
    float mu = s * (1.f / 192.f);
    float qv = 0.f;
    #pragma unroll
    for (int j = 0; j < 48; ++j) { float d = vals[j] - mu; qv += d * d; }
    qv += __shfl_xor(qv, 1); qv += __shfl_xor(qv, 2);
    float rstd = rsqrtf(qv * (1.f / 192.f) + 1e-5f);

    size_t row = (size_t)b * Ssz + w * Himg + h;
    float*  of = outf + row * Ed + q * 48;
    ushort* ob = outb + row * Ed + q * 48;
    const float* gg = g + q * 48;
    const float* bv = bb + q * 48;
    #pragma unroll
    for (int j = 0; j < 48; ++j) {
        float y = (vals[j] - mu) * rstd * gg[j] + bv[j];
        of[j] = y;
        ob[j] = f2b(y);
    }
}

// ---------------------------------------------------------------------------
// bf16 MFMA GEMM: BM=128 BN=64 BK=96; 256 thr / 4 waves.
// VOUT: Q cols -> QP[bh][s][32] (pre-scaled by log2(e)/sqrt(hd)),
//       K cols -> KP[bh][s][32], V cols -> VT[bh][d][s'] (kappa order).
template<int RELU, int RESID, int OBF, int VOUT>
__global__ __launch_bounds__(256) void gemm_mfma(
    const ushort* __restrict__ A, const ushort* __restrict__ Wt,
    const float* __restrict__ bias, const float* __restrict__ resid,
    float* __restrict__ C, ushort* __restrict__ Cb,
    ushort* __restrict__ qpout, ushort* __restrict__ kpout,
    ushort* __restrict__ vtout,
    int M, int N, int K)
{
    __shared__ __align__(16) ushort As[12288];   // 24 frags (8 msub x 3 ksub) * 1KB
    __shared__ __align__(16) ushort Bs[6144];    // 12 frags (4 nsub x 3 ksub) * 1KB
    const int tid  = threadIdx.x;
    const int lane = tid & 63;
    const int wave = tid >> 6;
    const int wr = wave >> 1, wc = wave & 1;
    const int bm = blockIdx.x * 128;
    const int bn = blockIdx.y * 64;

    const ushort* Ag[6]; ushort* Al[6];
    #pragma unroll
    for (int i = 0; i < 6; ++i) {
        int fa = 4 * i + wave;                 // 0..23
        int msub = fa / 3, ksub = fa % 3;
        int m = msub * 16 + (lane & 15);
        int k = ksub * 32 + ((lane >> 4) << 3);
        Ag[i] = A + (size_t)(bm + m) * K + k;
        Al[i] = As + fa * 512;                 // wave-uniform
    }
    const ushort* Bg[3]; ushort* Bl[3];
    #pragma unroll
    for (int i = 0; i < 3; ++i) {
        int fb = 4 * i + wave;                 // 0..11
        int nsub = fb / 3, ksub = fb % 3;
        int n = nsub * 16 + (lane & 15);
        int k = ksub * 32 + ((lane >> 4) << 3);
        Bg[i] = Wt + (size_t)(bn + n) * K + k;
        Bl[i] = Bs + fb * 512;
    }

    f32x4 acc[4][2];
    #pragma unroll
    for (int i = 0; i < 4; ++i)
        #pragma unroll
        for (int j = 0; j < 2; ++j) acc[i][j] = (f32x4){0.f, 0.f, 0.f, 0.f};

    for (int k0 = 0; k0 < K; k0 += 96) {
        #pragma unroll
        for (int i = 0; i < 6; ++i) gload16(Ag[i] + k0, Al[i], lane);
        #pragma unroll
        for (int i = 0; i < 3; ++i) gload16(Bg[i] + k0, Bl[i], lane);
        __syncthreads();
        #pragma unroll
        for (int ksub = 0; ksub < 3; ++ksub) {
            short8 af[4], bf[2];
            #pragma unroll
            for (int ms = 0; ms < 4; ++ms)
                af[ms] = *(const short8*)(As + (((wr*4+ms)*3 + ksub) * 64 + lane) * 8);
            #pragma unroll
            for (int ns = 0; ns < 2; ++ns)
                bf[ns] = *(const short8*)(Bs + (((wc*2+ns)*3 + ksub) * 64 + lane) * 8);
            #pragma unroll
            for (int ms = 0; ms < 4; ++ms)
                #pragma unroll
                for (int ns = 0; ns < 2; ++ns)
                    acc[ms][ns] = __builtin_amdgcn_mfma_f32_16x16x32_bf16(
                        af[ms], bf[ns], acc[ms][ns], 0, 0, 0);
        }
        __syncthreads();
    }

    int q = lane >> 4, colL = lane & 15;
    #pragma unroll
    for (int ms = 0; ms < 4; ++ms) {
        #pragma unroll
        for (int ns = 0; ns < 2; ++ns) {
            int row0 = bm + (wr*4 + ms) * 16 + q * 4;
            int col  = bn + (wc*2 + ns) * 16 + colL;
            float bvv = bias[col];
            float v[4];
            #pragma unroll
            for (int r = 0; r < 4; ++r) {
                v[r] = acc[ms][ns][r] + bvv;
                if (RELU) v[r] = fmaxf(v[r], 0.f);
                if (RESID) v[r] += resid[(size_t)(row0 + r) * N + col];
            }
            if (VOUT) {
                int bidx = row0 >> 9, srow = row0 & 511;
                if (col >= 384) {                 // V -> VT[bh][d][s'] (kappa)
                    int hh = (col - 384) >> 5, dd = (col - 384) & 31;
                    int sr = srow ^ ((((srow >> 2) ^ (srow >> 3)) & 1) * 12);
                    ushort4 pv;
                    pv.x = f2b(v[0]); pv.y = f2b(v[1]); pv.z = f2b(v[2]); pv.w = f2b(v[3]);
                    *(ushort4*)(vtout + (((size_t)(bidx * NHd + hh) * 32 + dd) << 9) + sr) = pv;
                } else {                          // Q/K -> {QP,KP}[bh][s][32]
                    ushort* dst = (col < 192) ? qpout : kpout;
                    int cc = (col < 192) ? col : col - 192;
                    if (col < 192) {              // fold log2(e)/sqrt(32) into Q
                        const float c2 = 0.2550547270628364f;
                        #pragma unroll
                        for (int r = 0; r < 4; ++r) v[r] *= c2;
                    }
                    int hh = cc >> 5, dd = cc & 31;
                    ushort* p = dst + ((size_t)(bidx * NHd + hh) << 14) + (size_t)srow * 32 + dd;
                    p[0]  = f2b(v[0]); p[32] = f2b(v[1]);
                    p[64] = f2b(v[2]); p[96] = f2b(v[3]);
                }
            } else {
                #pragma unroll
                for (int r = 0; r < 4; ++r) {
                    if (OBF) Cb[(size_t)(row0 + r) * N + col] = f2b(v[r]);
                    else     C [(size_t)(row0 + r) * N + col] = v[r];
                }
            }
        }
    }
}

// ---------------------------------------------------------------------------
// Fused GEMM (+bias +resid) + row-LN. N=192 fixed. Used for out-proj only.
// BM=64, BN=192, BK=64, 256 thr / 4 waves. K = KIT*64.
template<int KIT>
__global__ __launch_bounds__(256) void gemm_ln(
    const ushort* __restrict__ A, const ushort* __restrict__ Wt,
    const float* __restrict__ bias, const float* __restrict__ resid,
    const float* __restrict__ lng, const float* __restrict__ lnb,
    float* __restrict__ outf, ushort* __restrict__ outb)
{
    __shared__ __align__(16) ushort As[4096];    // 8 frags (4 msub x 2 ksub)
    __shared__ __align__(16) ushort Bs[12288];   // 24 frags (12 nsub x 2 ksub)
    const int K = KIT * 64;
    const int lane = threadIdx.x & 63;
    const int wave = threadIdx.x >> 6;
    const int g = lane >> 4, ql = lane & 15;
    const int bm = blockIdx.x * 64;

    const ushort* Gp[8]; ushort* Lp[8];
    #pragma unroll
    for (int i = 0; i < 8; ++i) {
        int f = 4 * i + wave;                    // 0..31
        if (f < 8) {
            int msub = f >> 1, ksub = f & 1;
            Gp[i] = A + (size_t)(bm + msub * 16 + ql) * K + ksub * 32 + g * 8;
            Lp[i] = As + f * 512;
        } else {
            int fb = f - 8, nsub = fb >> 1, ksub = fb & 1;
            Gp[i] = Wt + (size_t)(nsub * 16 + ql) * K + ksub * 32 + g * 8;
            Lp[i] = Bs + fb * 512;
        }
    }

    f32x4 acc[12];
    #pragma unroll
    for (int i = 0; i < 12; ++i) acc[i] = (f32x4){0.f, 0.f, 0.f, 0.f};

    for (int kc = 0; kc < KIT; ++kc) {
        #pragma unroll
        for (int i = 0; i < 8; ++i) gload16(Gp[i] + kc * 64, Lp[i], lane);
        __syncthreads();
        #pragma unroll
        for (int ksub = 0; ksub < 2; ++ksub) {
            short8 af = *(const short8*)(As + ((wave * 2 + ksub) * 64 + lane) * 8);
            #pragma unroll
            for (int ns = 0; ns < 12; ++ns) {
                short8 bf = *(const short8*)(Bs + ((ns * 2 + ksub) * 64 + lane) * 8);
                acc[ns] = __builtin_amdgcn_mfma_f32_16x16x32_bf16(af, bf, acc[ns], 0, 0, 0);
            }
        }
        __syncthreads();
    }

    float bi[12], gg[12], bb[12];
    #pragma unroll
    for (int ns = 0; ns < 12; ++ns) {
        int col = ns * 16 + ql;
        bi[ns] = bias[col];
        gg[ns] = lng[col]; bb[ns] = lnb[col];
    }
    #pragma unroll
    for (int r = 0; r < 4; ++r) {
        int row = bm + wave * 16 + g * 4 + r;
        float v[12];
        #pragma unroll
        for (int ns = 0; ns < 12; ++ns)
            v[ns] = acc[ns][r] + bi[ns] + resid[(size_t)row * Ed + ns * 16 + ql];
        float s = 0.f;
        #pragma unroll
        for (int ns = 0; ns < 12; ++ns) s += v[ns];
        s += __shfl_xor(s, 1); s += __shfl_xor(s, 2);
        s += __shfl_xor(s, 4); s += __shfl_xor(s, 8);
        float mu = s * (1.f / 192.f);
        float qv = 0.f;
        #pragma unroll
        for (int ns = 0; ns < 12; ++ns) { float d = v[ns] - mu; qv += d * d; }
        qv += __shfl_xor(qv, 1); qv += __shfl_xor(qv, 2);
        qv += __shfl_xor(qv, 4); qv += __shfl_xor(qv, 8);
        float rstd = rsqrtf(qv * (1.f / 192.f) + 1e-5f);
        #pragma unroll
        for (int ns = 0; ns < 12; ++ns) {
            float y = (v[ns] - mu) * rstd * gg[ns] + bb[ns];
            int col = ns * 16 + ql;
            outf[(size_t)row * Ed + col] = y;
            outb[(size_t)row * Ed + col] = f2b(y);
        }
    }
}

// ---------------------------------------------------------------------------
// FUSED MLP: Y = relu(X@W1^T + b1)@W2k^T + b2 + resid, then epilogue.
// H (32768x768 bf16) never leaves registers: per 32-col H-chunk, phase-1
// mfma(A=W1-frag, B=X-frag) gives C[h-col][x-row] (x-row on lane&15) --
// the SAME transpose shape as attention's S -- so the identical
// cvt_pk+permlane32_swap machinery converts it to phase-2 A-frags, with the
// kappa slot-permutation absorbed into W2k's k-column order (cvt_weights).
// Per wave: 16 rows; X preloaded (6 frags); Yacc[12] persistent; 24 chunks
// x (12 phase-1 + 12 phase-2 MFMAs). No LDS. grid Mrows/64, 4 waves.
// MODE=1: LN epilogue -> outf/outb. MODE=2: conv-im2col bf16 scatter.
template<int MODE>
__global__ __launch_bounds__(256) void fused_mlp(
    const ushort* __restrict__ X, const ushort* __restrict__ W1,
    const float* __restrict__ b1, const ushort* __restrict__ W2k,
    const float* __restrict__ b2, const float* __restrict__ resid,
    const float* __restrict__ lng, const float* __restrict__ lnb,
    float* __restrict__ outf, ushort* __restrict__ outb,
    ushort* __restrict__ a2out)
{
    const int lane = threadIdx.x & 63;
    const int wave = threadIdx.x >> 6;
    const int g = lane >> 4, ql = lane & 15;
    const int bm = blockIdx.x * 64;
    const int row16 = bm + wave * 16;            // this wave's 16 rows
    const f32x4 z = {0.f,0.f,0.f,0.f};

    short8 xf[6];                                // X B-frags: row=ql, k=g*8
    #pragma unroll
    for (int ks = 0; ks < 6; ++ks)
        xf[ks] = *(const short8*)(X + (size_t)(row16 + ql) * Ed + ks * 32 + g * 8);

    f32x4 yacc[12];
    #pragma unroll
    for (int i = 0; i < 12; ++i) yacc[i] = z;

    #pragma unroll
    for (int c = 0; c < 24; ++c) {
        // W2 B-frags for this k-chunk (independent -> in flight over phase 1)
        short8 w2f[12];
        #pragma unroll
        for (int n2 = 0; n2 < 12; ++n2)
            w2f[n2] = *(const short8*)(W2k + (size_t)(n2 * 16 + ql) * 768 + c * 32 + g * 8);
        // W1 A-frags (rows = h-cols of this chunk)
        short8 w1f0[6], w1f1[6];
        #pragma unroll
        for (int ks = 0; ks < 6; ++ks) {
            w1f0[ks] = *(const short8*)(W1 + (size_t)(c * 32 + ql) * Ed + ks * 32 + g * 8);
            w1f1[ks] = *(const short8*)(W1 + (size_t)(c * 32 + 16 + ql) * Ed + ks * 32 + g * 8);
        }
        float4 bA = *(const float4*)(b1 + c * 32 + 4 * g);
        float4 bB = *(const float4*)(b1 + c * 32 + 16 + 4 * g);

        f32x4 st0 = z, st1 = z;                  // C[h-col][x-row]
        #pragma unroll
        for (int ks = 0; ks < 6; ++ks) {
            st0 = __builtin_amdgcn_mfma_f32_16x16x32_bf16(w1f0[ks], xf[ks], st0, 0, 0, 0);
            st1 = __builtin_amdgcn_mfma_f32_16x16x32_bf16(w1f1[ks], xf[ks], st1, 0, 0, 0);
        }
        // bias + relu + pack + in-register transpose (attention's F)
        float p8[8];
        p8[0] = fmaxf(st0[0] + bA.x, 0.f);
        p8[1] = fmaxf(st0[1] + bA.y, 0.f);
        p8[2] = fmaxf(st0[2] + bA.z, 0.f);
        p8[3] = fmaxf(st0[3] + bA.w, 0.f);
        p8[4] = fmaxf(st1[0] + bB.x, 0.f);
        p8[5] = fmaxf(st1[1] + bB.y, 0.f);
        p8[6] = fmaxf(st1[2] + bB.z, 0.f);
        p8[7] = fmaxf(st1[3] + bB.w, 0.f);
        uint Au = cvt_pk_bf16(p8[0], p8[1]);
        uint Bu = cvt_pk_bf16(p8[2], p8[3]);
        uint Cu = cvt_pk_bf16(p8[4], p8[5]);
        uint Du = cvt_pk_bf16(p8[6], p8[7]);
        asm("v_permlane32_swap_b32 %0, %1" : "+v"(Au), "+v"(Cu));
        asm("v_permlane32_swap_b32 %0, %1" : "+v"(Bu), "+v"(Du));
        union { uint u[4]; short8 s; } pk;
        pk.u[0] = Au; pk.u[1] = Bu; pk.u[2] = Cu; pk.u[3] = Du;
        short8 pa = pk.s;                        // H A-frag, kappa slot order

        #pragma unroll
        for (int n2 = 0; n2 < 12; ++n2)
            yacc[n2] = __builtin_amdgcn_mfma_f32_16x16x32_bf16(pa, w2f[n2], yacc[n2], 0, 0, 0);
    }

    // epilogue (gemm_ln layout: row = row16 + g*4 + r, col = ns*16 + ql)
    float bi[12], gg[12], bb[12];
    #pragma unroll
    for (int ns = 0; ns < 12; ++ns) {
        int col = ns * 16 + ql;
        bi[ns] = b2[col];
        if (MODE == 1) { gg[ns] = lng[col]; bb[ns] = lnb[col]; }
    }
    #pragma unroll
    for (int r = 0; r < 4; ++r) {
        int row = row16 + g * 4 + r;
        float v[12];
        #pragma unroll
        for (int ns = 0; ns < 12; ++ns)
            v[ns] = yacc[ns][r] + bi[ns] + resid[(size_t)row * Ed + ns * 16 + ql];
        if (MODE == 1) {
            float s = 0.f;
            #pragma unroll
            for (int ns = 0; ns < 12; ++ns) s += v[ns];
            s += __shfl_xor(s, 1); s += __shfl_xor(s, 2);
            s += __shfl_xor(s, 4); s += __shfl_xor(s, 8);
            float mu = s * (1.f / 192.f);
            float qv = 0.f;
            #pragma unroll
            for (int ns = 0; ns < 12; ++ns) { float d = v[ns] - mu; qv += d * d; }
            qv += __shfl_xor(qv, 1); qv += __shfl_xor(qv, 2);
            qv += __shfl_xor(qv, 4); qv += __shfl_xor(qv, 8);
            float rstd = rsqrtf(qv * (1.f / 192.f) + 1e-5f);
            #pragma unroll
            for (int ns = 0; ns < 12; ++ns) {
                float y = (v[ns] - mu) * rstd * gg[ns] + bb[ns];
                int col = ns * 16 + ql;
                outf[(size_t)row * Ed + col] = y;
                outb[(size_t)row * Ed + col] = f2b(y);
            }
        } else {
            int bz = row >> 9, s = row & 511;
            int w = s >> 3, h = s & 7;
            #pragma unroll
            for (int ho = 0; ho < 4; ++ho) {
                int kh = h + 1 - 2 * ho;
                if (kh >= 0 && kh < 3) {
                    size_t r2 = ((size_t)((bz * 4 + ho) * 64 + w)) * 576 + kh * 192;
                    #pragma unroll
                    for (int ns = 0; ns < 12; ++ns)
                        a2out[r2 + ns * 16 + ql] = f2b(v[ns]);
                }
            }
            if (h == 0) {                       // top pad: hin = -1 stripe
                size_t r2 = ((size_t)(bz * 4 * 64 + w)) * 576;   // ho=0, kh=0
                #pragma unroll
                for (int ns = 0; ns < 12; ++ns)
                    a2out[r2 + ns * 16 + ql] = 0;
            }
        }
    }
}

// ---------------------------------------------------------------------------
// MFMA attention (round-5 best: 41.3 us), 2 q-tiles per wave (32 q x 512
// keys), LDS-free with in-register P transpose. Score stage pipelined one
// tile deep; K 3-deep, V 2-deep prefetch. grid (384 bh, 4); 4 waves.
template<int USE_MASK>
__global__ __launch_bounds__(256) void attn_mfma(const ushort* __restrict__ qp,
                                                 const ushort* __restrict__ kp,
                                                 const ushort* __restrict__ vt,
                                                 ushort* __restrict__ att) {
    const int bh = blockIdx.x;
    const int b = bh / NHd, h = bh % NHd;
    const int wave = threadIdx.x >> 6, lane = threadIdx.x & 63;
    const int g = lane >> 4, ql = lane & 15;
    const int qb = blockIdx.y * 128 + wave * 32;

    const ushort* qbase = qp + ((size_t)bh << 14);
    const ushort* kbase = kp + ((size_t)bh << 14);
    const ushort* vbase = vt + ((size_t)bh << 14);
    short8 qf[2];
    #pragma unroll
    for (int t = 0; t < 2; ++t)
        qf[t] = *(const short8*)(qbase + (size_t)(qb + t * 16 + ql) * 32 + g * 8);

    short8 onesf;
    #pragma unroll
    for (int j = 0; j < 8; ++j) onesf[j] = (short)0x3F80;   // bf16 1.0

    uint m0[2], m1[2]; int qh[2];
    if (USE_MASK) {
        #pragma unroll
        for (int t = 0; t < 2; ++t) {
            int qwt = ((qb + t * 16) & 63) + ql;      // no wrap: base%16==0
            qh[t] = (qb + t * 16) >> 6;
            uint a0 = 0, a1 = 0;
            #pragma unroll
            for (int i = 0; i < 8; ++i) {
                int keyl = (i >> 2) * 16 + 4 * g + (i & 3);
                int d0 = keyl - qwt;      d0 = d0 < 0 ? -d0 : d0;
                int d1 = keyl + 32 - qwt; d1 = d1 < 0 ? -d1 : d1;
                if (d0 <= 5) a0 |= (1u << i);
                if (d1 <= 5) a1 |= (1u << i);
            }
            m0[t] = a0; m1[t] = a1;
        }
    }

    f32x4 o0[2], o1[2], o2[2];
    #pragma unroll
    for (int t = 0; t < 2; ++t) {
        o0[t] = (f32x4){0.f,0.f,0.f,0.f};
        o1[t] = (f32x4){0.f,0.f,0.f,0.f};
        o2[t] = (f32x4){0.f,0.f,0.f,0.f};
    }
    const f32x4 z = {0.f,0.f,0.f,0.f};

    short8 kb_[3][2];     // K tiles, 3-deep rotation
    short8 vb_[2][2];     // V tiles, 2-deep rotation
    f32x4  st_[2][4];     // scores in flight, 2 tiles: [parity][t*2+half]
    short8 pa[2];         // transposed P A-frags for current tile

    auto LK = [&](int kt, short8* d) {
        d[0] = *(const short8*)(kbase + (size_t)(kt * 32 + ql) * 32 + g * 8);
        d[1] = *(const short8*)(kbase + (size_t)(kt * 32 + 16 + ql) * 32 + g * 8);
    };
    auto LV = [&](int kt, short8* d) {
        d[0] = *(const short8*)(vbase + (size_t)ql * 512 + kt * 32 + 8 * g);
        d[1] = *(const short8*)(vbase + (size_t)(16 + ql) * 512 + kt * 32 + 8 * g);
    };
    auto S = [&](const short8* k, f32x4* st) {    // 4 score MFMAs
        st[0] = __builtin_amdgcn_mfma_f32_16x16x32_bf16(k[0], qf[0], z, 0, 0, 0);
        st[1] = __builtin_amdgcn_mfma_f32_16x16x32_bf16(k[1], qf[0], z, 0, 0, 0);
        st[2] = __builtin_amdgcn_mfma_f32_16x16x32_bf16(k[0], qf[1], z, 0, 0, 0);
        st[3] = __builtin_amdgcn_mfma_f32_16x16x32_bf16(k[1], qf[1], z, 0, 0, 0);
    };
    auto F = [&](int kt, const f32x4* st) {       // exp2+mask+pack+transpose
        #pragma unroll
        for (int t = 0; t < 2; ++t) {
            float p8[8];
            #pragma unroll
            for (int r = 0; r < 4; ++r) {
                p8[r]     = fexp2(st[t*2][r]);
                p8[4 + r] = fexp2(st[t*2+1][r]);
            }
            if (USE_MASK) {
                int dh = (kt >> 1) - qh[t]; dh = dh < 0 ? -dh : dh;
                if (dh <= 3) {
                    uint mm = (kt & 1) ? m1[t] : m0[t];
                    #pragma unroll
                    for (int i = 0; i < 8; ++i)
                        if ((mm >> i) & 1u) p8[i] = 0.f;
                }
            }
            uint Au = cvt_pk_bf16(p8[0], p8[1]);   // keys 4g+0,4g+1
            uint Bu = cvt_pk_bf16(p8[2], p8[3]);   // keys 4g+2,4g+3
            uint Cu = cvt_pk_bf16(p8[4], p8[5]);   // keys 16+4g+0,+1
            uint Du = cvt_pk_bf16(p8[6], p8[7]);   // keys 16+4g+2,+3
            asm("v_permlane32_swap_b32 %0, %1" : "+v"(Au), "+v"(Cu));
            asm("v_permlane32_swap_b32 %0, %1" : "+v"(Bu), "+v"(Du));
            union { uint u[4]; short8 s; } pk;
            pk.u[0] = Au; pk.u[1] = Bu; pk.u[2] = Cu; pk.u[3] = Du;
            pa[t] = pk.s;                           // A-frag in kappa key-order
        }
    };
    auto PV = [&](const short8* v) {
        #pragma unroll
        for (int t = 0; t < 2; ++t) {
            o0[t] = __builtin_amdgcn_mfma_f32_16x16x32_bf16(pa[t], v[0], o0[t], 0, 0, 0);
            o1[t] = __builtin_amdgcn_mfma_f32_16x16x32_bf16(pa[t], v[1], o1[t], 0, 0, 0);
            o2[t] = __builtin_amdgcn_mfma_f32_16x16x32_bf16(pa[t], onesf, o2[t], 0, 0, 0);
        }
    };

    // --- pipelined loop over 16 key-tiles ----------------------------------
    LK(0, kb_[0]); LK(1, kb_[1]); LK(2, kb_[2]);
    LV(0, vb_[0]); LV(1, vb_[1]);
    S(kb_[0], st_[0]);
    #pragma unroll
    for (int kt = 0; kt < 16; ++kt) {
        if (kt < 15) S(kb_[(kt + 1) % 3], st_[(kt + 1) & 1]);  // next scores
        if (kt < 13) LK(kt + 3, kb_[kt % 3]);                  // K 3 ahead
        F(kt, st_[kt & 1]);                                    // finish cur
        __builtin_amdgcn_s_setprio(1);
        PV(vb_[kt & 1]);                                       // PV cur
        __builtin_amdgcn_s_setprio(0);
        if (kt < 14) LV(kt + 2, vb_[kt & 1]);                  // V 2 ahead
    }

    ushort* op = att + (size_t)b * Ssz * Ed + h * 32;
    #pragma unroll
    for (int t = 0; t < 2; ++t) {
        #pragma unroll
        for (int r = 0; r < 4; ++r) {
            float iv = 1.f / o2[t][r];
            int row = qb + t * 16 + 4 * g + r;
            op[(size_t)row * Ed + ql]      = f2b(o0[t][r] * iv);
            op[(size_t)row * Ed + 16 + ql] = f2b(o1[t][r] * iv);
        }
    }
}

// ---------------------------------------------------------------------------
// channel LN on conv output C2[r=(b*4+ho)*64+w][co=256] -> out[b,co,ho,w]
__global__ __launch_bounds__(256) void ln_out_kernel(const float* __restrict__ C2,
                                                     const float* __restrict__ g,
                                                     const float* __restrict__ beta,
                                                     float* __restrict__ out) {
    __shared__ float lds[32 * 257];
    int w0 = blockIdx.x * 32, ho = blockIdx.y, b = blockIdx.z;
    int tid = threadIdx.x;
    size_t rbase = ((size_t)b * 4 + ho) * 64 + w0;

    for (int i = 0; i < 32; ++i)
        lds[i * 257 + tid] = C2[(rbase + i) * COd + tid];
    __syncthreads();

    int wv = tid >> 6, lane = tid & 63;
    for (int rr = 0; rr < 8; ++rr) {
        int i = wv * 8 + rr;
        float v0 = lds[i*257 + lane], v1 = lds[i*257 + lane + 64];
        float v2 = lds[i*257 + lane + 128], v3 = lds[i*257 + lane + 192];
        float s = v0 + v1 + v2 + v3;
        #pragma unroll
        for (int off = 32; off > 0; off >>= 1) s += __shfl_xor(s, off);
        float mu = s * (1.f / 256.f);
        float d0 = v0-mu, d1 = v1-mu, d2 = v2-mu, d3 = v3-mu;
        float qv = d0*d0 + d1*d1 + d2*d2 + d3*d3;
        #pragma unroll
        for (int off = 32; off > 0; off >>= 1) qv += __shfl_xor(qv, off);
        float rstd = rsqrtf(qv * (1.f / 256.f) + 1e-5f);
        lds[i*257 + lane]       = d0 * rstd * g[lane]       + beta[lane];
        lds[i*257 + lane + 64]  = d1 * rstd * g[lane + 64]  + beta[lane + 64];
        lds[i*257 + lane + 128] = d2 * rstd * g[lane + 128] + beta[lane + 128];
        lds[i*257 + lane + 192] = d3 * rstd * g[lane + 192] + beta[lane + 192];
    }
    __syncthreads();

    int w = tid & 31, half = tid >> 5;
    for (int j = 0; j < 32; ++j) {
        int co = half + j * 8;
        out[(((size_t)b * COd + co) * 4 + ho) * Wimg + w0 + w] = lds[w * 257 + co];
    }
}

// ---------------------------------------------------------------------------
extern "C" void kernel_launch(void* const* d_in, const int* in_sizes, int n_in,
                              void* d_out, int out_size, void* d_ws, size_t ws_size,
                              hipStream_t stream) {
    const float* image = (const float*)d_in[0];
    const float* in_w  = (const float*)d_in[1];
    const float* in_b  = (const float*)d_in[2];
    const float* out_w = (const float*)d_in[3];
    const float* out_b = (const float*)d_in[4];
    const float* ln1_g = (const float*)d_in[5];
    const float* ln1_b = (const float*)d_in[6];
    const float* ln2_g = (const float*)d_in[7];
    const float* ln2_b = (const float*)d_in[8];
    const float* w1    = (const float*)d_in[9];
    const float* b1    = (const float*)d_in[10];
    const float* w2    = (const float*)d_in[11];
    const float* b2    = (const float*)d_in[12];
    const float* convw = (const float*)d_in[13];
    const float* convb = (const float*)d_in[14];
    const float* mln_g = (const float*)d_in[15];
    const float* mln_b = (const float*)d_in[16];
    float* out = (float*)d_out;
    float* ws  = (float*)d_ws;

    // ws layout (float units):
    //  F1 (x1 stream fp32)   [0, 6291456)
    //  F2 (x3 stream fp32)   [6291456, 12582912)
    //  BIG [12582912, 28311552):
    //       QP bf16 @BIG | KP @+3145728 | VT @+6291456
    //       C2 f32 @BIG+4718592 (conv path, end)
    //  XNb  bf16 @ BIG+12582912  [25165824, 28311552)
    //  A2b  bf16 @ ws+25165824 (aliases dead XNb+ATTb at conv time)
    //  ATTb bf16 [28311552, 31457280)
    //  Wb   bf16 [31457280, 32858112)
    float* F1   = ws;
    float* F2   = ws + 6291456;
    float* BIG  = ws + 12582912;
    ushort* QP   = (ushort*)BIG;
    ushort* KP   = (ushort*)(BIG + 3145728);
    ushort* VT   = (ushort*)(BIG + 6291456);
    float*  C2   = BIG + 4718592;
    ushort* XNb  = (ushort*)(BIG + 12582912);
    ushort* A2b  = (ushort*)(ws + 25165824);
    ushort* ATTb = (ushort*)(ws + 28311552);
    ushort* Wb   = (ushort*)(ws + 31457280);

    ushort* in_wb  = Wb;                    // 663552
    ushort* out_wb = Wb + 663552;           // 221184
    ushort* w1b    = Wb + 884736;           // 884736
    ushort* w2b    = Wb + 1769472;          // 884736 (kappa k-order)
    ushort* cwb    = Wb + 2654208;          // 147456

    cvt_weights<<<(2801664 + 255) / 256, 256, 0, stream>>>(
        in_w, out_w, w1, w2, convw, Wb);

    // fused reshape + layer-0 LN1: image -> F1 (x1 fp32) + XNb (x1 bf16)
    reshape_ln<<<Bn * Himg, 256, 0, stream>>>(image, ln1_g, ln1_b, F1, XNb);

    for (int i = 0; i < Ld; ++i) {
        gemm_mfma<0,0,1,1><<<dim3(Mrows/128, 9), 256, 0, stream>>>(
            XNb, in_wb + (size_t)i * 3*Ed*Ed, in_b + i * 3*Ed,
            nullptr, nullptr, nullptr, QP, KP, VT, Mrows, 3*Ed, Ed);
        if (i >= 2) attn_mfma<1><<<dim3(Bn * NHd, 4), 256, 0, stream>>>(QP, KP, VT, ATTb);
        else        attn_mfma<0><<<dim3(Bn * NHd, 4), 256, 0, stream>>>(QP, KP, VT, ATTb);
        // out-proj + x1 + LN2 -> F2 (x3 fp32) + XNb (x3 bf16)
        gemm_ln<3><<<Mrows/64, 256, 0, stream>>>(
            ATTb, out_wb + (size_t)i * Ed*Ed, out_b + i*Ed,
            F1, ln2_g + i*Ed, ln2_b + i*Ed, F2, XNb);
        // fused MLP (mlp1 + relu + mlp2 + resid + epilogue), H in registers
        if (i < Ld - 1) {
            fused_mlp<1><<<Mrows/64, 256, 0, stream>>>(
                XNb, w1b + (size_t)i * 4*Ed*Ed, b1 + i * 4*Ed,
                w2b + (size_t)i * 4*Ed*Ed, b2 + i*Ed, F2,
                ln1_g + (i+1)*Ed, ln1_b + (i+1)*Ed, F1, XNb, nullptr);
        } else {
            fused_mlp<2><<<Mrows/64, 256, 0, stream>>>(
                XNb, w1b + (size_t)i * 4*Ed*Ed, b1 + i * 4*Ed,
                w2b + (size_t)i * 4*Ed*Ed, b2 + i*Ed, F2,
                nullptr, nullptr, nullptr, nullptr, A2b);
        }
    }

    gemm_mfma<0,0,0,0><<<dim3(16384/128, 4), 256, 0, stream>>>(
        A2b, cwb, convb, nullptr, C2, nullptr, nullptr, nullptr, nullptr,
        16384, COd, 576);
    ln_out_kernel<<<dim3(2, 4, Bn), 256, 0, stream>>>(C2, mln_g, mln_b, out);
}

// Round 9
// 938.807 us; speedup vs baseline: 1.6374x; 1.6374x over previous
//
#include <hip/hip_runtime.h>
#include <hip/hip_bf16.h>
#include <math.h>

// Problem constants
#define Bn   64
#define Ssz  512     // W*H = 64*8
#define Ed   192
#define NHd  6
#define HDd  32
#define Ld   6
#define COd  256
#define Himg 8
#define Wimg 64
#define Mrows (Bn*Ssz)   // 32768

typedef unsigned int  uint;
typedef unsigned short ushort;
using short8 = __attribute__((ext_vector_type(8))) short;
using f32x4  = __attribute__((ext_vector_type(4))) float;

__device__ inline ushort f2b(float f) {          // fp32 -> bf16 RNE
    uint u = __builtin_bit_cast(uint, f);
    u = (u + 0x7FFFu + ((u >> 16) & 1u)) >> 16;
    return (ushort)u;
}

__device__ __forceinline__ float fexp2(float x) {
#if __has_builtin(__builtin_amdgcn_exp2f)
    return __builtin_amdgcn_exp2f(x);
#else
    return exp2f(x);
#endif
}

// packed f32x2 -> bf16x2 (lo = a, hi = b); no builtin on gfx950, inline asm
__device__ __forceinline__ uint cvt_pk_bf16(float a, float b) {
    uint r;
    asm("v_cvt_pk_bf16_f32 %0, %1, %2" : "=v"(r) : "v"(a), "v"(b));
    return r;
}

// async global->LDS 16B: lane i lands at lds + i*16 (wave-uniform lds base)
__device__ __forceinline__ void gload16(const ushort* g, ushort* l, int lane) {
#if __has_builtin(__builtin_amdgcn_global_load_lds)
    __builtin_amdgcn_global_load_lds(
        (const __attribute__((address_space(1))) uint*)g,
        (__attribute__((address_space(3))) uint*)l, 16, 0, 0);
#else
    *(uint4*)(l + (size_t)lane * 8) = *(const uint4*)g;
#endif
}

// ---------------------------------------------------------------------------
// ALL weight conversions in one dispatch:
//   [0, 663552)        in_w   -> Wb
//   [663552, 884736)   out_w
//   [884736, 1769472)  w1
//   [1769472, 2654208) w2  (k-columns kappa-permuted: k ^= 12 when bit2^bit3,
//                           matching fused_mlp's register-transposed H slots)
//   [2654208, 2801664) conv_w (transposed to [co][kh*192+c])
__global__ __launch_bounds__(256) void cvt_weights(const float* __restrict__ in_w,
                                                   const float* __restrict__ out_w,
                                                   const float* __restrict__ w1,
                                                   const float* __restrict__ w2,
                                                   const float* __restrict__ convw,
                                                   ushort* __restrict__ Wb) {
    int t = blockIdx.x * 256 + threadIdx.x;
    if (t >= 2801664) return;
    float v;
    if (t < 663552)        v = in_w[t];
    else if (t < 884736)   v = out_w[t - 663552];
    else if (t < 1769472)  v = w1[t - 884736];
    else if (t < 2654208) {
        int u = t - 1769472;
        int k = u % 768;
        int ks = k ^ ((((k >> 2) ^ (k >> 3)) & 1) * 12);
        v = w2[u - k + ks];
    } else {
        int u = t - 2654208;
        int co = u / 576, rem = u % 576;
        int kh = rem / Ed, c = rem % Ed;
        v = convw[((size_t)co * Ed + c) * 3 + kh];
    }
    Wb[t] = f2b(v);
}

// ---------------------------------------------------------------------------
// FUSED reshape + layer-0 LN1: image [B,E,8,64] -> LN over E at rows
// s = w*8 + h -> F1 fp32 + XNb bf16.
__global__ __launch_bounds__(256) void reshape_ln(const float* __restrict__ img,
                                                  const float* __restrict__ g,
                                                  const float* __restrict__ bb,
                                                  float* __restrict__ outf,
                                                  ushort* __restrict__ outb) {
    __shared__ float lds[Ed * 65];               // 49920 B
    const int b = blockIdx.x >> 3, h = blockIdx.x & 7;
    const int tid = threadIdx.x;
    const float* src = img + ((size_t)b * Ed * Himg + h) * Wimg;  // +c*512+w
    #pragma unroll
    for (int i = 0; i < 48; ++i) {
        int idx = i * 256 + tid;
        int c = idx >> 6, w = idx & 63;
        lds[c * 65 + w] = src[(size_t)c * 512 + w];
    }
    __syncthreads();

    const int w = tid >> 2, q = tid & 3;         // 4 lanes per row w
    float vals[48];
    float s = 0.f;
    #pragma unroll
    for (int j = 0; j < 48; ++j) {
        vals[j] = lds[(q * 48 + j) * 65 + w];
        s += vals[j];
    }
    s += __shfl_xor(s, 1); s += __shfl_xor(s, 2);
    float mu = s * (1.f / 192.f);
    float qv = 0.f;
    #pragma unroll
    for (int j = 0; j < 48; ++j) { float d = vals[j] - mu; qv += d * d; }
    qv += __shfl_xor(qv, 1); qv += __shfl_xor(qv, 2);
    float rstd = rsqrtf(qv * (1.f / 192.f) + 1e-5f);

    size_t row = (size_t)b * Ssz + w * Himg + h;
    float*  of = outf + row * Ed + q * 48;
    ushort* ob = outb + row * Ed + q * 48;
    const float* gg = g + q * 48;
    const float* bv = bb + q * 48;
    #pragma unroll
    for (int j = 0; j < 48; ++j) {
        float y = (vals[j] - mu) * rstd * gg[j] + bv[j];
        of[j] = y;
        ob[j] = f2b(y);
    }
}

// ---------------------------------------------------------------------------
// bf16 MFMA GEMM: BM=128 BN=64 BK=96; 256 thr / 4 waves.
// VOUT: Q cols -> QP[bh][s][32] (pre-scaled by log2(e)/sqrt(hd)),
//       K cols -> KP[bh][s][32], V cols -> VT[bh][d][s'] (kappa order).
template<int RELU, int RESID, int OBF, int VOUT>
__global__ __launch_bounds__(256) void gemm_mfma(
    const ushort* __restrict__ A, const ushort* __restrict__ Wt,
    const float* __restrict__ bias, const float* __restrict__ resid,
    float* __restrict__ C, ushort* __restrict__ Cb,
    ushort* __restrict__ qpout, ushort* __restrict__ kpout,
    ushort* __restrict__ vtout,
    int M, int N, int K)
{
    __shared__ __align__(16) ushort As[12288];   // 24 frags (8 msub x 3 ksub) * 1KB
    __shared__ __align__(16) ushort Bs[6144];    // 12 frags (4 nsub x 3 ksub) * 1KB
    const int tid  = threadIdx.x;
    const int lane = tid & 63;
    const int wave = tid >> 6;
    const int wr = wave >> 1, wc = wave & 1;
    const int bm = blockIdx.x * 128;
    const int bn = blockIdx.y * 64;

    const ushort* Ag[6]; ushort* Al[6];
    #pragma unroll
    for (int i = 0; i < 6; ++i) {
        int fa = 4 * i + wave;                 // 0..23
        int msub = fa / 3, ksub = fa % 3;
        int m = msub * 16 + (lane & 15);
        int k = ksub * 32 + ((lane >> 4) << 3);
        Ag[i] = A + (size_t)(bm + m) * K + k;
        Al[i] = As + fa * 512;                 // wave-uniform
    }
    const ushort* Bg[3]; ushort* Bl[3];
    #pragma unroll
    for (int i = 0; i < 3; ++i) {
        int fb = 4 * i + wave;                 // 0..11
        int nsub = fb / 3, ksub = fb % 3;
        int n = nsub * 16 + (lane & 15);
        int k = ksub * 32 + ((lane >> 4) << 3);
        Bg[i] = Wt + (size_t)(bn + n) * K + k;
        Bl[i] = Bs + fb * 512;
    }

    f32x4 acc[4][2];
    #pragma unroll
    for (int i = 0; i < 4; ++i)
        #pragma unroll
        for (int j = 0; j < 2; ++j) acc[i][j] = (f32x4){0.f, 0.f, 0.f, 0.f};

    for (int k0 = 0; k0 < K; k0 += 96) {
        #pragma unroll
        for (int i = 0; i < 6; ++i) gload16(Ag[i] + k0, Al[i], lane);
        #pragma unroll
        for (int i = 0; i < 3; ++i) gload16(Bg[i] + k0, Bl[i], lane);
        __syncthreads();
        #pragma unroll
        for (int ksub = 0; ksub < 3; ++ksub) {
            short8 af[4], bf[2];
            #pragma unroll
            for (int ms = 0; ms < 4; ++ms)
                af[ms] = *(const short8*)(As + (((wr*4+ms)*3 + ksub) * 64 + lane) * 8);
            #pragma unroll
            for (int ns = 0; ns < 2; ++ns)
                bf[ns] = *(const short8*)(Bs + (((wc*2+ns)*3 + ksub) * 64 + lane) * 8);
            #pragma unroll
            for (int ms = 0; ms < 4; ++ms)
                #pragma unroll
                for (int ns = 0; ns < 2; ++ns)
                    acc[ms][ns] = __builtin_amdgcn_mfma_f32_16x16x32_bf16(
                        af[ms], bf[ns], acc[ms][ns], 0, 0, 0);
        }
        __syncthreads();
    }

    int q = lane >> 4, colL = lane & 15;
    #pragma unroll
    for (int ms = 0; ms < 4; ++ms) {
        #pragma unroll
        for (int ns = 0; ns < 2; ++ns) {
            int row0 = bm + (wr*4 + ms) * 16 + q * 4;
            int col  = bn + (wc*2 + ns) * 16 + colL;
            float bvv = bias[col];
            float v[4];
            #pragma unroll
            for (int r = 0; r < 4; ++r) {
                v[r] = acc[ms][ns][r] + bvv;
                if (RELU) v[r] = fmaxf(v[r], 0.f);
                if (RESID) v[r] += resid[(size_t)(row0 + r) * N + col];
            }
            if (VOUT) {
                int bidx = row0 >> 9, srow = row0 & 511;
                if (col >= 384) {                 // V -> VT[bh][d][s'] (kappa)
                    int hh = (col - 384) >> 5, dd = (col - 384) & 31;
                    int sr = srow ^ ((((srow >> 2) ^ (srow >> 3)) & 1) * 12);
                    ushort4 pv;
                    pv.x = f2b(v[0]); pv.y = f2b(v[1]); pv.z = f2b(v[2]); pv.w = f2b(v[3]);
                    *(ushort4*)(vtout + (((size_t)(bidx * NHd + hh) * 32 + dd) << 9) + sr) = pv;
                } else {                          // Q/K -> {QP,KP}[bh][s][32]
                    ushort* dst = (col < 192) ? qpout : kpout;
                    int cc = (col < 192) ? col : col - 192;
                    if (col < 192) {              // fold log2(e)/sqrt(32) into Q
                        const float c2 = 0.2550547270628364f;
                        #pragma unroll
                        for (int r = 0; r < 4; ++r) v[r] *= c2;
                    }
                    int hh = cc >> 5, dd = cc & 31;
                    ushort* p = dst + ((size_t)(bidx * NHd + hh) << 14) + (size_t)srow * 32 + dd;
                    p[0]  = f2b(v[0]); p[32] = f2b(v[1]);
                    p[64] = f2b(v[2]); p[96] = f2b(v[3]);
                }
            } else {
                #pragma unroll
                for (int r = 0; r < 4; ++r) {
                    if (OBF) Cb[(size_t)(row0 + r) * N + col] = f2b(v[r]);
                    else     C [(size_t)(row0 + r) * N + col] = v[r];
                }
            }
        }
    }
}

// ---------------------------------------------------------------------------
// Fused GEMM (+bias +resid) + row-LN. N=192 fixed. Used for out-proj only.
// BM=64, BN=192, BK=64, 256 thr / 4 waves. K = KIT*64.
template<int KIT>
__global__ __launch_bounds__(256) void gemm_ln(
    const ushort* __restrict__ A, const ushort* __restrict__ Wt,
    const float* __restrict__ bias, const float* __restrict__ resid,
    const float* __restrict__ lng, const float* __restrict__ lnb,
    float* __restrict__ outf, ushort* __restrict__ outb)
{
    __shared__ __align__(16) ushort As[4096];    // 8 frags (4 msub x 2 ksub)
    __shared__ __align__(16) ushort Bs[12288];   // 24 frags (12 nsub x 2 ksub)
    const int K = KIT * 64;
    const int lane = threadIdx.x & 63;
    const int wave = threadIdx.x >> 6;
    const int g = lane >> 4, ql = lane & 15;
    const int bm = blockIdx.x * 64;

    const ushort* Gp[8]; ushort* Lp[8];
    #pragma unroll
    for (int i = 0; i < 8; ++i) {
        int f = 4 * i + wave;                    // 0..31
        if (f < 8) {
            int msub = f >> 1, ksub = f & 1;
            Gp[i] = A + (size_t)(bm + msub * 16 + ql) * K + ksub * 32 + g * 8;
            Lp[i] = As + f * 512;
        } else {
            int fb = f - 8, nsub = fb >> 1, ksub = fb & 1;
            Gp[i] = Wt + (size_t)(nsub * 16 + ql) * K + ksub * 32 + g * 8;
            Lp[i] = Bs + fb * 512;
        }
    }

    f32x4 acc[12];
    #pragma unroll
    for (int i = 0; i < 12; ++i) acc[i] = (f32x4){0.f, 0.f, 0.f, 0.f};

    for (int kc = 0; kc < KIT; ++kc) {
        #pragma unroll
        for (int i = 0; i < 8; ++i) gload16(Gp[i] + kc * 64, Lp[i], lane);
        __syncthreads();
        #pragma unroll
        for (int ksub = 0; ksub < 2; ++ksub) {
            short8 af = *(const short8*)(As + ((wave * 2 + ksub) * 64 + lane) * 8);
            #pragma unroll
            for (int ns = 0; ns < 12; ++ns) {
                short8 bf = *(const short8*)(Bs + ((ns * 2 + ksub) * 64 + lane) * 8);
                acc[ns] = __builtin_amdgcn_mfma_f32_16x16x32_bf16(af, bf, acc[ns], 0, 0, 0);
            }
        }
        __syncthreads();
    }

    float bi[12], gg[12], bb[12];
    #pragma unroll
    for (int ns = 0; ns < 12; ++ns) {
        int col = ns * 16 + ql;
        bi[ns] = bias[col];
        gg[ns] = lng[col]; bb[ns] = lnb[col];
    }
    #pragma unroll
    for (int r = 0; r < 4; ++r) {
        int row = bm + wave * 16 + g * 4 + r;
        float v[12];
        #pragma unroll
        for (int ns = 0; ns < 12; ++ns)
            v[ns] = acc[ns][r] + bi[ns] + resid[(size_t)row * Ed + ns * 16 + ql];
        float s = 0.f;
        #pragma unroll
        for (int ns = 0; ns < 12; ++ns) s += v[ns];
        s += __shfl_xor(s, 1); s += __shfl_xor(s, 2);
        s += __shfl_xor(s, 4); s += __shfl_xor(s, 8);
        float mu = s * (1.f / 192.f);
        float qv = 0.f;
        #pragma unroll
        for (int ns = 0; ns < 12; ++ns) { float d = v[ns] - mu; qv += d * d; }
        qv += __shfl_xor(qv, 1); qv += __shfl_xor(qv, 2);
        qv += __shfl_xor(qv, 4); qv += __shfl_xor(qv, 8);
        float rstd = rsqrtf(qv * (1.f / 192.f) + 1e-5f);
        #pragma unroll
        for (int ns = 0; ns < 12; ++ns) {
            float y = (v[ns] - mu) * rstd * gg[ns] + bb[ns];
            int col = ns * 16 + ql;
            outf[(size_t)row * Ed + col] = y;
            outb[(size_t)row * Ed + col] = f2b(y);
        }
    }
}

// ---------------------------------------------------------------------------
// FUSED MLP v2: Y = relu(X@W1^T + b1)@W2k^T + b2 + resid, then epilogue.
// H never leaves registers. Round-8 failure was latency (each wave issued
// 576 private global weight loads, MfmaUtil 4.7%); v2 stages each 32-h-col
// weight chunk in LDS via global_load_lds, SHARED by the block's 4 waves and
// double-buffered: STAGE(c+1) is issued right after the barrier that
// publishes chunk c, so its latency hides under chunk c's 24 ds_read +
// 24 MFMA. Phase-1 C-layout -> phase-2 A-frag via the attention transpose
// (cvt_pk + permlane32_swap); kappa absorbed in W2k column order.
// LDS 48 KB (2 x 24 frags x 1KB). grid Mrows/64, 4 waves.
// MODE=1: LN epilogue. MODE=2: conv-im2col bf16 scatter.
template<int MODE>
__global__ __launch_bounds__(256) void fused_mlp(
    const ushort* __restrict__ X, const ushort* __restrict__ W1,
    const float* __restrict__ b1, const ushort* __restrict__ W2k,
    const float* __restrict__ b2, const float* __restrict__ resid,
    const float* __restrict__ lng, const float* __restrict__ lnb,
    float* __restrict__ outf, ushort* __restrict__ outb,
    ushort* __restrict__ a2out)
{
    __shared__ __align__(16) ushort Ws[2][24][512];   // 48 KB
    const int lane = threadIdx.x & 63;
    const int wave = threadIdx.x >> 6;
    const int g = lane >> 4, ql = lane & 15;
    const int bm = blockIdx.x * 64;
    const int row16 = bm + wave * 16;            // this wave's 16 rows
    const f32x4 z = {0.f,0.f,0.f,0.f};

    short8 xf[6];                                // X B-frags: row=ql, k=g*8
    #pragma unroll
    for (int ks = 0; ks < 6; ++ks)
        xf[ks] = *(const short8*)(X + (size_t)(row16 + ql) * Ed + ks * 32 + g * 8);

    // this wave's 6 staged frags: f = 4*i + wave; f<12: W1 (hsub=f/6,ksub=f%6)
    // stride/chunk 32*Ed; f>=12: W2 (n2=f-12), stride/chunk 32.
    const ushort* gsrc[6]; ushort* ldst[6]; int strd[6];
    #pragma unroll
    for (int i = 0; i < 6; ++i) {
        int f = 4 * i + wave;
        if (f < 12) {
            int hsub = f / 6, ksub = f % 6;
            gsrc[i] = W1 + (size_t)(hsub * 16 + ql) * Ed + ksub * 32 + g * 8;
            strd[i] = 32 * Ed;
        } else {
            int n2 = f - 12;
            gsrc[i] = W2k + (size_t)(n2 * 16 + ql) * 768 + g * 8;
            strd[i] = 32;
        }
        ldst[i] = &Ws[0][f][0];                  // buffer 1 = +24*512
    }
    auto STAGE = [&](int c, int b) {
        #pragma unroll
        for (int i = 0; i < 6; ++i)
            gload16(gsrc[i] + (size_t)c * strd[i], ldst[i] + b * 12288, lane);
    };

    f32x4 yacc[12];
    #pragma unroll
    for (int i = 0; i < 12; ++i) yacc[i] = z;

    STAGE(0, 0);
    #pragma unroll
    for (int c = 0; c < 24; ++c) {
        __syncthreads();                          // publishes buf[c&1]
        if (c < 23) STAGE(c + 1, (c + 1) & 1);    // in flight over compute
        const ushort* wb = &Ws[c & 1][0][0];

        // bias for this chunk (L1-resident after first block)
        float4 bA = *(const float4*)(b1 + c * 32 + 4 * g);
        float4 bB = *(const float4*)(b1 + c * 32 + 16 + 4 * g);

        f32x4 st0 = z, st1 = z;                   // C[h-col][x-row]
        #pragma unroll
        for (int ks = 0; ks < 6; ++ks) {
            short8 a0 = *(const short8*)(wb + (size_t)ks * 512 + lane * 8);
            short8 a1 = *(const short8*)(wb + (size_t)(6 + ks) * 512 + lane * 8);
            st0 = __builtin_amdgcn_mfma_f32_16x16x32_bf16(a0, xf[ks], st0, 0, 0, 0);
            st1 = __builtin_amdgcn_mfma_f32_16x16x32_bf16(a1, xf[ks], st1, 0, 0, 0);
        }
        // bias + relu + pack + in-register transpose (attention's F)
        float p8[8];
        p8[0] = fmaxf(st0[0] + bA.x, 0.f);
        p8[1] = fmaxf(st0[1] + bA.y, 0.f);
        p8[2] = fmaxf(st0[2] + bA.z, 0.f);
        p8[3] = fmaxf(st0[3] + bA.w, 0.f);
        p8[4] = fmaxf(st1[0] + bB.x, 0.f);
        p8[5] = fmaxf(st1[1] + bB.y, 0.f);
        p8[6] = fmaxf(st1[2] + bB.z, 0.f);
        p8[7] = fmaxf(st1[3] + bB.w, 0.f);
        uint Au = cvt_pk_bf16(p8[0], p8[1]);
        uint Bu = cvt_pk_bf16(p8[2], p8[3]);
        uint Cu = cvt_pk_bf16(p8[4], p8[5]);
        uint Du = cvt_pk_bf16(p8[6], p8[7]);
        asm("v_permlane32_swap_b32 %0, %1" : "+v"(Au), "+v"(Cu));
        asm("v_permlane32_swap_b32 %0, %1" : "+v"(Bu), "+v"(Du));
        union { uint u[4]; short8 s; } pk;
        pk.u[0] = Au; pk.u[1] = Bu; pk.u[2] = Cu; pk.u[3] = Du;
        short8 pa = pk.s;                         // H A-frag, kappa slot order

        #pragma unroll
        for (int n2 = 0; n2 < 12; ++n2) {
            short8 bfr = *(const short8*)(wb + (size_t)(12 + n2) * 512 + lane * 8);
            yacc[n2] = __builtin_amdgcn_mfma_f32_16x16x32_bf16(pa, bfr, yacc[n2], 0, 0, 0);
        }
    }

    // epilogue (gemm_ln layout: row = row16 + g*4 + r, col = ns*16 + ql)
    float bi[12], gg[12], bb[12];
    #pragma unroll
    for (int ns = 0; ns < 12; ++ns) {
        int col = ns * 16 + ql;
        bi[ns] = b2[col];
        if (MODE == 1) { gg[ns] = lng[col]; bb[ns] = lnb[col]; }
    }
    #pragma unroll
    for (int r = 0; r < 4; ++r) {
        int row = row16 + g * 4 + r;
        float v[12];
        #pragma unroll
        for (int ns = 0; ns < 12; ++ns)
            v[ns] = yacc[ns][r] + bi[ns] + resid[(size_t)row * Ed + ns * 16 + ql];
        if (MODE == 1) {
            float s = 0.f;
            #pragma unroll
            for (int ns = 0; ns < 12; ++ns) s += v[ns];
            s += __shfl_xor(s, 1); s += __shfl_xor(s, 2);
            s += __shfl_xor(s, 4); s += __shfl_xor(s, 8);
            float mu = s * (1.f / 192.f);
            float qv = 0.f;
            #pragma unroll
            for (int ns = 0; ns < 12; ++ns) { float d = v[ns] - mu; qv += d * d; }
            qv += __shfl_xor(qv, 1); qv += __shfl_xor(qv, 2);
            qv += __shfl_xor(qv, 4); qv += __shfl_xor(qv, 8);
            float rstd = rsqrtf(qv * (1.f / 192.f) + 1e-5f);
            #pragma unroll
            for (int ns = 0; ns < 12; ++ns) {
                float y = (v[ns] - mu) * rstd * gg[ns] + bb[ns];
                int col = ns * 16 + ql;
                outf[(size_t)row * Ed + col] = y;
                outb[(size_t)row * Ed + col] = f2b(y);
            }
        } else {
            int bz = row >> 9, s = row & 511;
            int w = s >> 3, h = s & 7;
            #pragma unroll
            for (int ho = 0; ho < 4; ++ho) {
                int kh = h + 1 - 2 * ho;
                if (kh >= 0 && kh < 3) {
                    size_t r2 = ((size_t)((bz * 4 + ho) * 64 + w)) * 576 + kh * 192;
                    #pragma unroll
                    for (int ns = 0; ns < 12; ++ns)
                        a2out[r2 + ns * 16 + ql] = f2b(v[ns]);
                }
            }
            if (h == 0) {                       // top pad: hin = -1 stripe
                size_t r2 = ((size_t)(bz * 4 * 64 + w)) * 576;   // ho=0, kh=0
                #pragma unroll
                for (int ns = 0; ns < 12; ++ns)
                    a2out[r2 + ns * 16 + ql] = 0;
            }
        }
    }
}

// ---------------------------------------------------------------------------
// MFMA attention (round-5 best: 41.3 us), 2 q-tiles per wave (32 q x 512
// keys), LDS-free with in-register P transpose. Score stage pipelined one
// tile deep; K 3-deep, V 2-deep prefetch. grid (384 bh, 4); 4 waves.
template<int USE_MASK>
__global__ __launch_bounds__(256) void attn_mfma(const ushort* __restrict__ qp,
                                                 const ushort* __restrict__ kp,
                                                 const ushort* __restrict__ vt,
                                                 ushort* __restrict__ att) {
    const int bh = blockIdx.x;
    const int b = bh / NHd, h = bh % NHd;
    const int wave = threadIdx.x >> 6, lane = threadIdx.x & 63;
    const int g = lane >> 4, ql = lane & 15;
    const int qb = blockIdx.y * 128 + wave * 32;

    const ushort* qbase = qp + ((size_t)bh << 14);
    const ushort* kbase = kp + ((size_t)bh << 14);
    const ushort* vbase = vt + ((size_t)bh << 14);
    short8 qf[2];
    #pragma unroll
    for (int t = 0; t < 2; ++t)
        qf[t] = *(const short8*)(qbase + (size_t)(qb + t * 16 + ql) * 32 + g * 8);

    short8 onesf;
    #pragma unroll
    for (int j = 0; j < 8; ++j) onesf[j] = (short)0x3F80;   // bf16 1.0

    uint m0[2], m1[2]; int qh[2];
    if (USE_MASK) {
        #pragma unroll
        for (int t = 0; t < 2; ++t) {
            int qwt = ((qb + t * 16) & 63) + ql;      // no wrap: base%16==0
            qh[t] = (qb + t * 16) >> 6;
            uint a0 = 0, a1 = 0;
            #pragma unroll
            for (int i = 0; i < 8; ++i) {
                int keyl = (i >> 2) * 16 + 4 * g + (i & 3);
                int d0 = keyl - qwt;      d0 = d0 < 0 ? -d0 : d0;
                int d1 = keyl + 32 - qwt; d1 = d1 < 0 ? -d1 : d1;
                if (d0 <= 5) a0 |= (1u << i);
                if (d1 <= 5) a1 |= (1u << i);
            }
            m0[t] = a0; m1[t] = a1;
        }
    }

    f32x4 o0[2], o1[2], o2[2];
    #pragma unroll
    for (int t = 0; t < 2; ++t) {
        o0[t] = (f32x4){0.f,0.f,0.f,0.f};
        o1[t] = (f32x4){0.f,0.f,0.f,0.f};
        o2[t] = (f32x4){0.f,0.f,0.f,0.f};
    }
    const f32x4 z = {0.f,0.f,0.f,0.f};

    short8 kb_[3][2];     // K tiles, 3-deep rotation
    short8 vb_[2][2];     // V tiles, 2-deep rotation
    f32x4  st_[2][4];     // scores in flight, 2 tiles: [parity][t*2+half]
    short8 pa[2];         // transposed P A-frags for current tile

    auto LK = [&](int kt, short8* d) {
        d[0] = *(const short8*)(kbase + (size_t)(kt * 32 + ql) * 32 + g * 8);
        d[1] = *(const short8*)(kbase + (size_t)(kt * 32 + 16 + ql) * 32 + g * 8);
    };
    auto LV = [&](int kt, short8* d) {
        d[0] = *(const short8*)(vbase + (size_t)ql * 512 + kt * 32 + 8 * g);
        d[1] = *(const short8*)(vbase + (size_t)(16 + ql) * 512 + kt * 32 + 8 * g);
    };
    auto S = [&](const short8* k, f32x4* st) {    // 4 score MFMAs
        st[0] = __builtin_amdgcn_mfma_f32_16x16x32_bf16(k[0], qf[0], z, 0, 0, 0);
        st[1] = __builtin_amdgcn_mfma_f32_16x16x32_bf16(k[1], qf[0], z, 0, 0, 0);
        st[2] = __builtin_amdgcn_mfma_f32_16x16x32_bf16(k[0], qf[1], z, 0, 0, 0);
        st[3] = __builtin_amdgcn_mfma_f32_16x16x32_bf16(k[1], qf[1], z, 0, 0, 0);
    };
    auto F = [&](int kt, const f32x4* st) {       // exp2+mask+pack+transpose
        #pragma unroll
        for (int t = 0; t < 2; ++t) {
            float p8[8];
            #pragma unroll
            for (int r = 0; r < 4; ++r) {
                p8[r]     = fexp2(st[t*2][r]);
                p8[4 + r] = fexp2(st[t*2+1][r]);
            }
            if (USE_MASK) {
                int dh = (kt >> 1) - qh[t]; dh = dh < 0 ? -dh : dh;
                if (dh <= 3) {
                    uint mm = (kt & 1) ? m1[t] : m0[t];
                    #pragma unroll
                    for (int i = 0; i < 8; ++i)
                        if ((mm >> i) & 1u) p8[i] = 0.f;
                }
            }
            uint Au = cvt_pk_bf16(p8[0], p8[1]);   // keys 4g+0,4g+1
            uint Bu = cvt_pk_bf16(p8[2], p8[3]);   // keys 4g+2,4g+3
            uint Cu = cvt_pk_bf16(p8[4], p8[5]);   // keys 16+4g+0,+1
            uint Du = cvt_pk_bf16(p8[6], p8[7]);   // keys 16+4g+2,+3
            asm("v_permlane32_swap_b32 %0, %1" : "+v"(Au), "+v"(Cu));
            asm("v_permlane32_swap_b32 %0, %1" : "+v"(Bu), "+v"(Du));
            union { uint u[4]; short8 s; } pk;
            pk.u[0] = Au; pk.u[1] = Bu; pk.u[2] = Cu; pk.u[3] = Du;
            pa[t] = pk.s;                           // A-frag in kappa key-order
        }
    };
    auto PV = [&](const short8* v) {
        #pragma unroll
        for (int t = 0; t < 2; ++t) {
            o0[t] = __builtin_amdgcn_mfma_f32_16x16x32_bf16(pa[t], v[0], o0[t], 0, 0, 0);
            o1[t] = __builtin_amdgcn_mfma_f32_16x16x32_bf16(pa[t], v[1], o1[t], 0, 0, 0);
            o2[t] = __builtin_amdgcn_mfma_f32_16x16x32_bf16(pa[t], onesf, o2[t], 0, 0, 0);
        }
    };

    // --- pipelined loop over 16 key-tiles ----------------------------------
    LK(0, kb_[0]); LK(1, kb_[1]); LK(2, kb_[2]);
    LV(0, vb_[0]); LV(1, vb_[1]);
    S(kb_[0], st_[0]);
    #pragma unroll
    for (int kt = 0; kt < 16; ++kt) {
        if (kt < 15) S(kb_[(kt + 1) % 3], st_[(kt + 1) & 1]);  // next scores
        if (kt < 13) LK(kt + 3, kb_[kt % 3]);                  // K 3 ahead
        F(kt, st_[kt & 1]);                                    // finish cur
        __builtin_amdgcn_s_setprio(1);
        PV(vb_[kt & 1]);                                       // PV cur
        __builtin_amdgcn_s_setprio(0);
        if (kt < 14) LV(kt + 2, vb_[kt & 1]);                  // V 2 ahead
    }

    ushort* op = att + (size_t)b * Ssz * Ed + h * 32;
    #pragma unroll
    for (int t = 0; t < 2; ++t) {
        #pragma unroll
        for (int r = 0; r < 4; ++r) {
            float iv = 1.f / o2[t][r];
            int row = qb + t * 16 + 4 * g + r;
            op[(size_t)row * Ed + ql]      = f2b(o0[t][r] * iv);
            op[(size_t)row * Ed + 16 + ql] = f2b(o1[t][r] * iv);
        }
    }
}

// ---------------------------------------------------------------------------
// channel LN on conv output C2[r=(b*4+ho)*64+w][co=256] -> out[b,co,ho,w]
__global__ __launch_bounds__(256) void ln_out_kernel(const float* __restrict__ C2,
                                                     const float* __restrict__ g,
                                                     const float* __restrict__ beta,
                                                     float* __restrict__ out) {
    __shared__ float lds[32 * 257];
    int w0 = blockIdx.x * 32, ho = blockIdx.y, b = blockIdx.z;
    int tid = threadIdx.x;
    size_t rbase = ((size_t)b * 4 + ho) * 64 + w0;

    for (int i = 0; i < 32; ++i)
        lds[i * 257 + tid] = C2[(rbase + i) * COd + tid];
    __syncthreads();

    int wv = tid >> 6, lane = tid & 63;
    for (int rr = 0; rr < 8; ++rr) {
        int i = wv * 8 + rr;
        float v0 = lds[i*257 + lane], v1 = lds[i*257 + lane + 64];
        float v2 = lds[i*257 + lane + 128], v3 = lds[i*257 + lane + 192];
        float s = v0 + v1 + v2 + v3;
        #pragma unroll
        for (int off = 32; off > 0; off >>= 1) s += __shfl_xor(s, off);
        float mu = s * (1.f / 256.f);
        float d0 = v0-mu, d1 = v1-mu, d2 = v2-mu, d3 = v3-mu;
        float qv = d0*d0 + d1*d1 + d2*d2 + d3*d3;
        #pragma unroll
        for (int off = 32; off > 0; off >>= 1) qv += __shfl_xor(qv, off);
        float rstd = rsqrtf(qv * (1.f / 256.f) + 1e-5f);
        lds[i*257 + lane]       = d0 * rstd * g[lane]       + beta[lane];
        lds[i*257 + lane + 64]  = d1 * rstd * g[lane + 64]  + beta[lane + 64];
        lds[i*257 + lane + 128] = d2 * rstd * g[lane + 128] + beta[lane + 128];
        lds[i*257 + lane + 192] = d3 * rstd * g[lane + 192] + beta[lane + 192];
    }
    __syncthreads();

    int w = tid & 31, half = tid >> 5;
    for (int j = 0; j < 32; ++j) {
        int co = half + j * 8;
        out[(((size_t)b * COd + co) * 4 + ho) * Wimg + w0 + w] = lds[w * 257 + co];
    }
}

// ---------------------------------------------------------------------------
extern "C" void kernel_launch(void* const* d_in, const int* in_sizes, int n_in,
                              void* d_out, int out_size, void* d_ws, size_t ws_size,
                              hipStream_t stream) {
    const float* image = (const float*)d_in[0];
    const float* in_w  = (const float*)d_in[1];
    const float* in_b  = (const float*)d_in[2];
    const float* out_w = (const float*)d_in[3];
    const float* out_b = (const float*)d_in[4];
    const float* ln1_g = (const float*)d_in[5];
    const float* ln1_b = (const float*)d_in[6];
    const float* ln2_g = (const float*)d_in[7];
    const float* ln2_b = (const float*)d_in[8];
    const float* w1    = (const float*)d_in[9];
    const float* b1    = (const float*)d_in[10];
    const float* w2    = (const float*)d_in[11];
    const float* b2    = (const float*)d_in[12];
    const float* convw = (const float*)d_in[13];
    const float* convb = (const float*)d_in[14];
    const float* mln_g = (const float*)d_in[15];
    const float* mln_b = (const float*)d_in[16];
    float* out = (float*)d_out;
    float* ws  = (float*)d_ws;

    // ws layout (float units):
    //  F1 (x1 stream fp32)   [0, 6291456)
    //  F2 (x3 stream fp32)   [6291456, 12582912)
    //  BIG [12582912, 28311552):
    //       QP bf16 @BIG | KP @+3145728 | VT @+6291456
    //       C2 f32 @BIG+4718592 (conv path, end)
    //  XNb  bf16 @ BIG+12582912  [25165824, 28311552)
    //  A2b  bf16 @ ws+25165824 (aliases dead XNb+ATTb at conv time)
    //  ATTb bf16 [28311552, 31457280)
    //  Wb   bf16 [31457280, 32858112)
    float* F1   = ws;
    float* F2   = ws + 6291456;
    float* BIG  = ws + 12582912;
    ushort* QP   = (ushort*)BIG;
    ushort* KP   = (ushort*)(BIG + 3145728);
    ushort* VT   = (ushort*)(BIG + 6291456);
    float*  C2   = BIG + 4718592;
    ushort* XNb  = (ushort*)(BIG + 12582912);
    ushort* A2b  = (ushort*)(ws + 25165824);
    ushort* ATTb = (ushort*)(ws + 28311552);
    ushort* Wb   = (ushort*)(ws + 31457280);

    ushort* in_wb  = Wb;                    // 663552
    ushort* out_wb = Wb + 663552;           // 221184
    ushort* w1b    = Wb + 884736;           // 884736
    ushort* w2b    = Wb + 1769472;          // 884736 (kappa k-order)
    ushort* cwb    = Wb + 2654208;          // 147456

    cvt_weights<<<(2801664 + 255) / 256, 256, 0, stream>>>(
        in_w, out_w, w1, w2, convw, Wb);

    // fused reshape + layer-0 LN1: image -> F1 (x1 fp32) + XNb (x1 bf16)
    reshape_ln<<<Bn * Himg, 256, 0, stream>>>(image, ln1_g, ln1_b, F1, XNb);

    for (int i = 0; i < Ld; ++i) {
        gemm_mfma<0,0,1,1><<<dim3(Mrows/128, 9), 256, 0, stream>>>(
            XNb, in_wb + (size_t)i * 3*Ed*Ed, in_b + i * 3*Ed,
            nullptr, nullptr, nullptr, QP, KP, VT, Mrows, 3*Ed, Ed);
        if (i >= 2) attn_mfma<1><<<dim3(Bn * NHd, 4), 256, 0, stream>>>(QP, KP, VT, ATTb);
        else        attn_mfma<0><<<dim3(Bn * NHd, 4), 256, 0, stream>>>(QP, KP, VT, ATTb);
        // out-proj + x1 + LN2 -> F2 (x3 fp32) + XNb (x3 bf16)
        gemm_ln<3><<<Mrows/64, 256, 0, stream>>>(
            ATTb, out_wb + (size_t)i * Ed*Ed, out_b + i*Ed,
            F1, ln2_g + i*Ed, ln2_b + i*Ed, F2, XNb);
        // fused MLP (mlp1 + relu + mlp2 + resid + epilogue), H in registers
        if (i < Ld - 1) {
            fused_mlp<1><<<Mrows/64, 256, 0, stream>>>(
                XNb, w1b + (size_t)i * 4*Ed*Ed, b1 + i * 4*Ed,
                w2b + (size_t)i * 4*Ed*Ed, b2 + i*Ed, F2,
                ln1_g + (i+1)*Ed, ln1_b + (i+1)*Ed, F1, XNb, nullptr);
        } else {
            fused_mlp<2><<<Mrows/64, 256, 0, stream>>>(
                XNb, w1b + (size_t)i * 4*Ed*Ed, b1 + i * 4*Ed,
                w2b + (size_t)i * 4*Ed*Ed, b2 + i*Ed, F2,
                nullptr, nullptr, nullptr, nullptr, A2b);
        }
    }

    gemm_mfma<0,0,0,0><<<dim3(16384/128, 4), 256, 0, stream>>>(
        A2b, cwb, convb, nullptr, C2, nullptr, nullptr, nullptr, nullptr,
        16384, COd, 576);
    ln_out_kernel<<<dim3(2, 4, Bn), 256, 0, stream>>>(C2, mln_g, mln_b, out);
}

// Round 10
// 925.340 us; speedup vs baseline: 1.6612x; 1.0146x over previous
//
#include <hip/hip_runtime.h>
#include <hip/hip_bf16.h>
#include <math.h>

// Problem constants
#define Bn   64
#define Ssz  512     // W*H = 64*8
#define Ed   192
#define NHd  6
#define HDd  32
#define Ld   6
#define COd  256
#define Himg 8
#define Wimg 64
#define Mrows (Bn*Ssz)   // 32768

typedef unsigned int  uint;
typedef unsigned short ushort;
using short8 = __attribute__((ext_vector_type(8))) short;
using f32x4  = __attribute__((ext_vector_type(4))) float;

__device__ inline ushort f2b(float f) {          // fp32 -> bf16 RNE
    uint u = __builtin_bit_cast(uint, f);
    u = (u + 0x7FFFu + ((u >> 16) & 1u)) >> 16;
    return (ushort)u;
}

__device__ __forceinline__ float fexp2(float x) {
#if __has_builtin(__builtin_amdgcn_exp2f)
    return __builtin_amdgcn_exp2f(x);
#else
    return exp2f(x);
#endif
}

// packed f32x2 -> bf16x2 (lo = a, hi = b); no builtin on gfx950, inline asm
__device__ __forceinline__ uint cvt_pk_bf16(float a, float b) {
    uint r;
    asm("v_cvt_pk_bf16_f32 %0, %1, %2" : "=v"(r) : "v"(a), "v"(b));
    return r;
}

// async global->LDS 16B: lane i lands at lds + i*16 (wave-uniform lds base)
__device__ __forceinline__ void gload16(const ushort* g, ushort* l, int lane) {
#if __has_builtin(__builtin_amdgcn_global_load_lds)
    __builtin_amdgcn_global_load_lds(
        (const __attribute__((address_space(1))) uint*)g,
        (__attribute__((address_space(3))) uint*)l, 16, 0, 0);
#else
    *(uint4*)(l + (size_t)lane * 8) = *(const uint4*)g;
#endif
}

// ---------------------------------------------------------------------------
// ALL weight conversions in one dispatch:
//   [0, 663552)        in_w   -> Wb
//   [663552, 884736)   out_w
//   [884736, 1769472)  w1
//   [1769472, 2654208) w2  (k-columns kappa-permuted: k ^= 12 when bit2^bit3,
//                           matching fused_mlp's register-transposed H slots)
//   [2654208, 2801664) conv_w (transposed to [co][kh*192+c])
__global__ __launch_bounds__(256) void cvt_weights(const float* __restrict__ in_w,
                                                   const float* __restrict__ out_w,
                                                   const float* __restrict__ w1,
                                                   const float* __restrict__ w2,
                                                   const float* __restrict__ convw,
                                                   ushort* __restrict__ Wb) {
    int t = blockIdx.x * 256 + threadIdx.x;
    if (t >= 2801664) return;
    float v;
    if (t < 663552)        v = in_w[t];
    else if (t < 884736)   v = out_w[t - 663552];
    else if (t < 1769472)  v = w1[t - 884736];
    else if (t < 2654208) {
        int u = t - 1769472;
        int k = u % 768;
        int ks = k ^ ((((k >> 2) ^ (k >> 3)) & 1) * 12);
        v = w2[u - k + ks];
    } else {
        int u = t - 2654208;
        int co = u / 576, rem = u % 576;
        int kh = rem / Ed, c = rem % Ed;
        v = convw[((size_t)co * Ed + c) * 3 + kh];
    }
    Wb[t] = f2b(v);
}

// ---------------------------------------------------------------------------
// FUSED reshape + layer-0 LN1: image [B,E,8,64] -> LN over E at rows
// s = w*8 + h -> F1 fp32 + XNb bf16.
__global__ __launch_bounds__(256) void reshape_ln(const float* __restrict__ img,
                                                  const float* __restrict__ g,
                                                  const float* __restrict__ bb,
                                                  float* __restrict__ outf,
                                                  ushort* __restrict__ outb) {
    __shared__ float lds[Ed * 65];               // 49920 B
    const int b = blockIdx.x >> 3, h = blockIdx.x & 7;
    const int tid = threadIdx.x;
    const float* src = img + ((size_t)b * Ed * Himg + h) * Wimg;  // +c*512+w
    #pragma unroll
    for (int i = 0; i < 48; ++i) {
        int idx = i * 256 + tid;
        int c = idx >> 6, w = idx & 63;
        lds[c * 65 + w] = src[(size_t)c * 512 + w];
    }
    __syncthreads();

    const int w = tid >> 2, q = tid & 3;         // 4 lanes per row w
    float vals[48];
    float s = 0.f;
    #pragma unroll
    for (int j = 0; j < 48; ++j) {
        vals[j] = lds[(q * 48 + j) * 65 + w];
        s += vals[j];
    }
    s += __shfl_xor(s, 1); s += __shfl_xor(s, 2);
    float mu = s * (1.f / 192.f);
    float qv = 0.f;
    #pragma unroll
    for (int j = 0; j < 48; ++j) { float d = vals[j] - mu; qv += d * d; }
    qv += __shfl_xor(qv, 1); qv += __shfl_xor(qv, 2);
    float rstd = rsqrtf(qv * (1.f / 192.f) + 1e-5f);

    size_t row = (size_t)b * Ssz + w * Himg + h;
    float*  of = outf + row * Ed + q * 48;
    ushort* ob = outb + row * Ed + q * 48;
    const float* gg = g + q * 48;
    const float* bv = bb + q * 48;
    #pragma unroll
    for (int j = 0; j < 48; ++j) {
        float y = (vals[j] - mu) * rstd * gg[j] + bv[j];
        of[j] = y;
        ob[j] = f2b(y);
    }
}

// ---------------------------------------------------------------------------
// bf16 MFMA GEMM: BM=128 BN=64 BK=96; 256 thr / 4 waves.
// VOUT: Q cols -> QP[bh][s][32] (pre-scaled by log2(e)/sqrt(hd)),
//       K cols -> KP[bh][s][32], V cols -> VT[bh][d][s'] (kappa order).
template<int RELU, int RESID, int OBF, int VOUT>
__global__ __launch_bounds__(256) void gemm_mfma(
    const ushort* __restrict__ A, const ushort* __restrict__ Wt,
    const float* __restrict__ bias, const float* __restrict__ resid,
    float* __restrict__ C, ushort* __restrict__ Cb,
    ushort* __restrict__ qpout, ushort* __restrict__ kpout,
    ushort* __restrict__ vtout,
    int M, int N, int K)
{
    __shared__ __align__(16) ushort As[12288];   // 24 frags (8 msub x 3 ksub) * 1KB
    __shared__ __align__(16) ushort Bs[6144];    // 12 frags (4 nsub x 3 ksub) * 1KB
    const int tid  = threadIdx.x;
    const int lane = tid & 63;
    const int wave = tid >> 6;
    const int wr = wave >> 1, wc = wave & 1;
    const int bm = blockIdx.x * 128;
    const int bn = blockIdx.y * 64;

    const ushort* Ag[6]; ushort* Al[6];
    #pragma unroll
    for (int i = 0; i < 6; ++i) {
        int fa = 4 * i + wave;                 // 0..23
        int msub = fa / 3, ksub = fa % 3;
        int m = msub * 16 + (lane & 15);
        int k = ksub * 32 + ((lane >> 4) << 3);
        Ag[i] = A + (size_t)(bm + m) * K + k;
        Al[i] = As + fa * 512;                 // wave-uniform
    }
    const ushort* Bg[3]; ushort* Bl[3];
    #pragma unroll
    for (int i = 0; i < 3; ++i) {
        int fb = 4 * i + wave;                 // 0..11
        int nsub = fb / 3, ksub = fb % 3;
        int n = nsub * 16 + (lane & 15);
        int k = ksub * 32 + ((lane >> 4) << 3);
        Bg[i] = Wt + (size_t)(bn + n) * K + k;
        Bl[i] = Bs + fb * 512;
    }

    f32x4 acc[4][2];
    #pragma unroll
    for (int i = 0; i < 4; ++i)
        #pragma unroll
        for (int j = 0; j < 2; ++j) acc[i][j] = (f32x4){0.f, 0.f, 0.f, 0.f};

    for (int k0 = 0; k0 < K; k0 += 96) {
        #pragma unroll
        for (int i = 0; i < 6; ++i) gload16(Ag[i] + k0, Al[i], lane);
        #pragma unroll
        for (int i = 0; i < 3; ++i) gload16(Bg[i] + k0, Bl[i], lane);
        __syncthreads();
        #pragma unroll
        for (int ksub = 0; ksub < 3; ++ksub) {
            short8 af[4], bf[2];
            #pragma unroll
            for (int ms = 0; ms < 4; ++ms)
                af[ms] = *(const short8*)(As + (((wr*4+ms)*3 + ksub) * 64 + lane) * 8);
            #pragma unroll
            for (int ns = 0; ns < 2; ++ns)
                bf[ns] = *(const short8*)(Bs + (((wc*2+ns)*3 + ksub) * 64 + lane) * 8);
            #pragma unroll
            for (int ms = 0; ms < 4; ++ms)
                #pragma unroll
                for (int ns = 0; ns < 2; ++ns)
                    acc[ms][ns] = __builtin_amdgcn_mfma_f32_16x16x32_bf16(
                        af[ms], bf[ns], acc[ms][ns], 0, 0, 0);
        }
        __syncthreads();
    }

    int q = lane >> 4, colL = lane & 15;
    #pragma unroll
    for (int ms = 0; ms < 4; ++ms) {
        #pragma unroll
        for (int ns = 0; ns < 2; ++ns) {
            int row0 = bm + (wr*4 + ms) * 16 + q * 4;
            int col  = bn + (wc*2 + ns) * 16 + colL;
            float bvv = bias[col];
            float v[4];
            #pragma unroll
            for (int r = 0; r < 4; ++r) {
                v[r] = acc[ms][ns][r] + bvv;
                if (RELU) v[r] = fmaxf(v[r], 0.f);
                if (RESID) v[r] += resid[(size_t)(row0 + r) * N + col];
            }
            if (VOUT) {
                int bidx = row0 >> 9, srow = row0 & 511;
                if (col >= 384) {                 // V -> VT[bh][d][s'] (kappa)
                    int hh = (col - 384) >> 5, dd = (col - 384) & 31;
                    int sr = srow ^ ((((srow >> 2) ^ (srow >> 3)) & 1) * 12);
                    ushort4 pv;
                    pv.x = f2b(v[0]); pv.y = f2b(v[1]); pv.z = f2b(v[2]); pv.w = f2b(v[3]);
                    *(ushort4*)(vtout + (((size_t)(bidx * NHd + hh) * 32 + dd) << 9) + sr) = pv;
                } else {                          // Q/K -> {QP,KP}[bh][s][32]
                    ushort* dst = (col < 192) ? qpout : kpout;
                    int cc = (col < 192) ? col : col - 192;
                    if (col < 192) {              // fold log2(e)/sqrt(32) into Q
                        const float c2 = 0.2550547270628364f;
                        #pragma unroll
                        for (int r = 0; r < 4; ++r) v[r] *= c2;
                    }
                    int hh = cc >> 5, dd = cc & 31;
                    ushort* p = dst + ((size_t)(bidx * NHd + hh) << 14) + (size_t)srow * 32 + dd;
                    p[0]  = f2b(v[0]); p[32] = f2b(v[1]);
                    p[64] = f2b(v[2]); p[96] = f2b(v[3]);
                }
            } else {
                #pragma unroll
                for (int r = 0; r < 4; ++r) {
                    if (OBF) Cb[(size_t)(row0 + r) * N + col] = f2b(v[r]);
                    else     C [(size_t)(row0 + r) * N + col] = v[r];
                }
            }
        }
    }
}

// ---------------------------------------------------------------------------
// Fused GEMM (+bias +resid) + row-LN. N=192 fixed. Used for out-proj only.
// BM=64, BN=192, BK=64, 256 thr / 4 waves. K = KIT*64.
template<int KIT>
__global__ __launch_bounds__(256) void gemm_ln(
    const ushort* __restrict__ A, const ushort* __restrict__ Wt,
    const float* __restrict__ bias, const float* __restrict__ resid,
    const float* __restrict__ lng, const float* __restrict__ lnb,
    float* __restrict__ outf, ushort* __restrict__ outb)
{
    __shared__ __align__(16) ushort As[4096];    // 8 frags (4 msub x 2 ksub)
    __shared__ __align__(16) ushort Bs[12288];   // 24 frags (12 nsub x 2 ksub)
    const int K = KIT * 64;
    const int lane = threadIdx.x & 63;
    const int wave = threadIdx.x >> 6;
    const int g = lane >> 4, ql = lane & 15;
    const int bm = blockIdx.x * 64;

    const ushort* Gp[8]; ushort* Lp[8];
    #pragma unroll
    for (int i = 0; i < 8; ++i) {
        int f = 4 * i + wave;                    // 0..31
        if (f < 8) {
            int msub = f >> 1, ksub = f & 1;
            Gp[i] = A + (size_t)(bm + msub * 16 + ql) * K + ksub * 32 + g * 8;
            Lp[i] = As + f * 512;
        } else {
            int fb = f - 8, nsub = fb >> 1, ksub = fb & 1;
            Gp[i] = Wt + (size_t)(nsub * 16 + ql) * K + ksub * 32 + g * 8;
            Lp[i] = Bs + fb * 512;
        }
    }

    f32x4 acc[12];
    #pragma unroll
    for (int i = 0; i < 12; ++i) acc[i] = (f32x4){0.f, 0.f, 0.f, 0.f};

    for (int kc = 0; kc < KIT; ++kc) {
        #pragma unroll
        for (int i = 0; i < 8; ++i) gload16(Gp[i] + kc * 64, Lp[i], lane);
        __syncthreads();
        #pragma unroll
        for (int ksub = 0; ksub < 2; ++ksub) {
            short8 af = *(const short8*)(As + ((wave * 2 + ksub) * 64 + lane) * 8);
            #pragma unroll
            for (int ns = 0; ns < 12; ++ns) {
                short8 bf = *(const short8*)(Bs + ((ns * 2 + ksub) * 64 + lane) * 8);
                acc[ns] = __builtin_amdgcn_mfma_f32_16x16x32_bf16(af, bf, acc[ns], 0, 0, 0);
            }
        }
        __syncthreads();
    }

    float bi[12], gg[12], bb[12];
    #pragma unroll
    for (int ns = 0; ns < 12; ++ns) {
        int col = ns * 16 + ql;
        bi[ns] = bias[col];
        gg[ns] = lng[col]; bb[ns] = lnb[col];
    }
    #pragma unroll
    for (int r = 0; r < 4; ++r) {
        int row = bm + wave * 16 + g * 4 + r;
        float v[12];
        #pragma unroll
        for (int ns = 0; ns < 12; ++ns)
            v[ns] = acc[ns][r] + bi[ns] + resid[(size_t)row * Ed + ns * 16 + ql];
        float s = 0.f;
        #pragma unroll
        for (int ns = 0; ns < 12; ++ns) s += v[ns];
        s += __shfl_xor(s, 1); s += __shfl_xor(s, 2);
        s += __shfl_xor(s, 4); s += __shfl_xor(s, 8);
        float mu = s * (1.f / 192.f);
        float qv = 0.f;
        #pragma unroll
        for (int ns = 0; ns < 12; ++ns) { float d = v[ns] - mu; qv += d * d; }
        qv += __shfl_xor(qv, 1); qv += __shfl_xor(qv, 2);
        qv += __shfl_xor(qv, 4); qv += __shfl_xor(qv, 8);
        float rstd = rsqrtf(qv * (1.f / 192.f) + 1e-5f);
        #pragma unroll
        for (int ns = 0; ns < 12; ++ns) {
            float y = (v[ns] - mu) * rstd * gg[ns] + bb[ns];
            int col = ns * 16 + ql;
            outf[(size_t)row * Ed + col] = y;
            outb[(size_t)row * Ed + col] = f2b(y);
        }
    }
}

// ---------------------------------------------------------------------------
// FUSED MLP v3: Y = relu(X@W1^T + b1)@W2k^T + b2 + resid, then epilogue.
// v2 (56 us) was latency-bound (MfmaUtil 13%, 2 waves/SIMD, serial
// barrier->P1->pack->P2 chain). v3 pipelines PHASE-1 ONE CHUNK AHEAD
// (attention round-4 pattern): 3 LDS buffers (72 KB -- free, grid already
// limits to 2 blocks/CU), per iter: barrier -> STAGE(c+2) -> P1(c+1) ->
// pack(c) -> P2(c). P1(c+1)'s 12 MFMAs decouple the barrier from the
// dependent pack->P2 chain; P2 covers next iter's STAGE/P1 latency.
// Safety: STAGE(c+2) overwrites buf last read by P2(c-1) -- protected by
// the top barrier; P1(c+1) reads buf staged at iter c-1, drained by the
// same barrier's vmcnt(0). kappa absorbed in W2k column order.
// MODE=1: LN epilogue. MODE=2: conv-im2col bf16 scatter.
template<int MODE>
__global__ __launch_bounds__(256) void fused_mlp(
    const ushort* __restrict__ X, const ushort* __restrict__ W1,
    const float* __restrict__ b1, const ushort* __restrict__ W2k,
    const float* __restrict__ b2, const float* __restrict__ resid,
    const float* __restrict__ lng, const float* __restrict__ lnb,
    float* __restrict__ outf, ushort* __restrict__ outb,
    ushort* __restrict__ a2out)
{
    __shared__ __align__(16) ushort Ws[3][24][512];   // 72 KB
    const int lane = threadIdx.x & 63;
    const int wave = threadIdx.x >> 6;
    const int g = lane >> 4, ql = lane & 15;
    const int bm = blockIdx.x * 64;
    const int row16 = bm + wave * 16;            // this wave's 16 rows
    const f32x4 z = {0.f,0.f,0.f,0.f};

    short8 xf[6];                                // X B-frags: row=ql, k=g*8
    #pragma unroll
    for (int ks = 0; ks < 6; ++ks)
        xf[ks] = *(const short8*)(X + (size_t)(row16 + ql) * Ed + ks * 32 + g * 8);

    // this wave's 6 staged frags: f = 4*i + wave; f<12: W1 (hsub=f/6,ksub=f%6)
    // stride/chunk 32*Ed; f>=12: W2 (n2=f-12), stride/chunk 32.
    const ushort* gsrc[6]; ushort* ldst[6]; int strd[6];
    #pragma unroll
    for (int i = 0; i < 6; ++i) {
        int f = 4 * i + wave;
        if (f < 12) {
            int hsub = f / 6, ksub = f % 6;
            gsrc[i] = W1 + (size_t)(hsub * 16 + ql) * Ed + ksub * 32 + g * 8;
            strd[i] = 32 * Ed;
        } else {
            int n2 = f - 12;
            gsrc[i] = W2k + (size_t)(n2 * 16 + ql) * 768 + g * 8;
            strd[i] = 32;
        }
        ldst[i] = &Ws[0][f][0];
    }
    auto STAGE = [&](int c) {
        int b = c % 3;
        #pragma unroll
        for (int i = 0; i < 6; ++i)
            gload16(gsrc[i] + (size_t)c * strd[i], ldst[i] + b * 12288, lane);
    };

    f32x4 yacc[12];
    #pragma unroll
    for (int i = 0; i < 12; ++i) yacc[i] = z;

    f32x4 st_[2][2];                             // scores, 2 chunks in flight

    auto P1 = [&](int c) {                       // 12 MFMAs -> st_[c&1]
        const ushort* wb = &Ws[c % 3][0][0];
        f32x4 s0 = z, s1 = z;
        #pragma unroll
        for (int ks = 0; ks < 6; ++ks) {
            short8 a0 = *(const short8*)(wb + (size_t)ks * 512 + lane * 8);
            short8 a1 = *(const short8*)(wb + (size_t)(6 + ks) * 512 + lane * 8);
            s0 = __builtin_amdgcn_mfma_f32_16x16x32_bf16(a0, xf[ks], s0, 0, 0, 0);
            s1 = __builtin_amdgcn_mfma_f32_16x16x32_bf16(a1, xf[ks], s1, 0, 0, 0);
        }
        st_[c & 1][0] = s0; st_[c & 1][1] = s1;
    };
    auto PACK = [&](int c) -> short8 {           // bias+relu+pack+transpose
        float4 bA = *(const float4*)(b1 + c * 32 + 4 * g);
        float4 bB = *(const float4*)(b1 + c * 32 + 16 + 4 * g);
        const f32x4 s0 = st_[c & 1][0], s1 = st_[c & 1][1];
        float p8[8];
        p8[0] = fmaxf(s0[0] + bA.x, 0.f);
        p8[1] = fmaxf(s0[1] + bA.y, 0.f);
        p8[2] = fmaxf(s0[2] + bA.z, 0.f);
        p8[3] = fmaxf(s0[3] + bA.w, 0.f);
        p8[4] = fmaxf(s1[0] + bB.x, 0.f);
        p8[5] = fmaxf(s1[1] + bB.y, 0.f);
        p8[6] = fmaxf(s1[2] + bB.z, 0.f);
        p8[7] = fmaxf(s1[3] + bB.w, 0.f);
        uint Au = cvt_pk_bf16(p8[0], p8[1]);
        uint Bu = cvt_pk_bf16(p8[2], p8[3]);
        uint Cu = cvt_pk_bf16(p8[4], p8[5]);
        uint Du = cvt_pk_bf16(p8[6], p8[7]);
        asm("v_permlane32_swap_b32 %0, %1" : "+v"(Au), "+v"(Cu));
        asm("v_permlane32_swap_b32 %0, %1" : "+v"(Bu), "+v"(Du));
        union { uint u[4]; short8 s; } pk;
        pk.u[0] = Au; pk.u[1] = Bu; pk.u[2] = Cu; pk.u[3] = Du;
        return pk.s;                             // H A-frag, kappa slot order
    };
    auto P2 = [&](int c, short8 pa) {            // 12 MFMAs -> yacc
        const ushort* wb = &Ws[c % 3][0][0];
        #pragma unroll
        for (int n2 = 0; n2 < 12; ++n2) {
            short8 bfr = *(const short8*)(wb + (size_t)(12 + n2) * 512 + lane * 8);
            yacc[n2] = __builtin_amdgcn_mfma_f32_16x16x32_bf16(pa, bfr, yacc[n2], 0, 0, 0);
        }
    };

    STAGE(0); STAGE(1);
    __syncthreads();                             // buf0, buf1 ready
    P1(0);
    #pragma unroll
    for (int c = 0; c < 24; ++c) {
        if (c > 0) __syncthreads();              // buf c+1 ready; buf (c+2)%3 free
        if (c < 22) STAGE(c + 2);
        if (c < 23) P1(c + 1);
        short8 pa = PACK(c);
        __builtin_amdgcn_s_setprio(1);
        P2(c, pa);
        __builtin_amdgcn_s_setprio(0);
    }

    // epilogue (gemm_ln layout: row = row16 + g*4 + r, col = ns*16 + ql)
    float bi[12], gg[12], bb[12];
    #pragma unroll
    for (int ns = 0; ns < 12; ++ns) {
        int col = ns * 16 + ql;
        bi[ns] = b2[col];
        if (MODE == 1) { gg[ns] = lng[col]; bb[ns] = lnb[col]; }
    }
    #pragma unroll
    for (int r = 0; r < 4; ++r) {
        int row = row16 + g * 4 + r;
        float v[12];
        #pragma unroll
        for (int ns = 0; ns < 12; ++ns)
            v[ns] = yacc[ns][r] + bi[ns] + resid[(size_t)row * Ed + ns * 16 + ql];
        if (MODE == 1) {
            float s = 0.f;
            #pragma unroll
            for (int ns = 0; ns < 12; ++ns) s += v[ns];
            s += __shfl_xor(s, 1); s += __shfl_xor(s, 2);
            s += __shfl_xor(s, 4); s += __shfl_xor(s, 8);
            float mu = s * (1.f / 192.f);
            float qv = 0.f;
            #pragma unroll
            for (int ns = 0; ns < 12; ++ns) { float d = v[ns] - mu; qv += d * d; }
            qv += __shfl_xor(qv, 1); qv += __shfl_xor(qv, 2);
            qv += __shfl_xor(qv, 4); qv += __shfl_xor(qv, 8);
            float rstd = rsqrtf(qv * (1.f / 192.f) + 1e-5f);
            #pragma unroll
            for (int ns = 0; ns < 12; ++ns) {
                float y = (v[ns] - mu) * rstd * gg[ns] + bb[ns];
                int col = ns * 16 + ql;
                outf[(size_t)row * Ed + col] = y;
                outb[(size_t)row * Ed + col] = f2b(y);
            }
        } else {
            int bz = row >> 9, s = row & 511;
            int w = s >> 3, h = s & 7;
            #pragma unroll
            for (int ho = 0; ho < 4; ++ho) {
                int kh = h + 1 - 2 * ho;
                if (kh >= 0 && kh < 3) {
                    size_t r2 = ((size_t)((bz * 4 + ho) * 64 + w)) * 576 + kh * 192;
                    #pragma unroll
                    for (int ns = 0; ns < 12; ++ns)
                        a2out[r2 + ns * 16 + ql] = f2b(v[ns]);
                }
            }
            if (h == 0) {                       // top pad: hin = -1 stripe
                size_t r2 = ((size_t)(bz * 4 * 64 + w)) * 576;   // ho=0, kh=0
                #pragma unroll
                for (int ns = 0; ns < 12; ++ns)
                    a2out[r2 + ns * 16 + ql] = 0;
            }
        }
    }
}

// ---------------------------------------------------------------------------
// MFMA attention (round-5 best: 41.3 us), 2 q-tiles per wave (32 q x 512
// keys), LDS-free with in-register P transpose. Score stage pipelined one
// tile deep; K 3-deep, V 2-deep prefetch. grid (384 bh, 4); 4 waves.
template<int USE_MASK>
__global__ __launch_bounds__(256) void attn_mfma(const ushort* __restrict__ qp,
                                                 const ushort* __restrict__ kp,
                                                 const ushort* __restrict__ vt,
                                                 ushort* __restrict__ att) {
    const int bh = blockIdx.x;
    const int b = bh / NHd, h = bh % NHd;
    const int wave = threadIdx.x >> 6, lane = threadIdx.x & 63;
    const int g = lane >> 4, ql = lane & 15;
    const int qb = blockIdx.y * 128 + wave * 32;

    const ushort* qbase = qp + ((size_t)bh << 14);
    const ushort* kbase = kp + ((size_t)bh << 14);
    const ushort* vbase = vt + ((size_t)bh << 14);
    short8 qf[2];
    #pragma unroll
    for (int t = 0; t < 2; ++t)
        qf[t] = *(const short8*)(qbase + (size_t)(qb + t * 16 + ql) * 32 + g * 8);

    short8 onesf;
    #pragma unroll
    for (int j = 0; j < 8; ++j) onesf[j] = (short)0x3F80;   // bf16 1.0

    uint m0[2], m1[2]; int qh[2];
    if (USE_MASK) {
        #pragma unroll
        for (int t = 0; t < 2; ++t) {
            int qwt = ((qb + t * 16) & 63) + ql;      // no wrap: base%16==0
            qh[t] = (qb + t * 16) >> 6;
            uint a0 = 0, a1 = 0;
            #pragma unroll
            for (int i = 0; i < 8; ++i) {
                int keyl = (i >> 2) * 16 + 4 * g + (i & 3);
                int d0 = keyl - qwt;      d0 = d0 < 0 ? -d0 : d0;
                int d1 = keyl + 32 - qwt; d1 = d1 < 0 ? -d1 : d1;
                if (d0 <= 5) a0 |= (1u << i);
                if (d1 <= 5) a1 |= (1u << i);
            }
            m0[t] = a0; m1[t] = a1;
        }
    }

    f32x4 o0[2], o1[2], o2[2];
    #pragma unroll
    for (int t = 0; t < 2; ++t) {
        o0[t] = (f32x4){0.f,0.f,0.f,0.f};
        o1[t] = (f32x4){0.f,0.f,0.f,0.f};
        o2[t] = (f32x4){0.f,0.f,0.f,0.f};
    }
    const f32x4 z = {0.f,0.f,0.f,0.f};

    short8 kb_[3][2];     // K tiles, 3-deep rotation
    short8 vb_[2][2];     // V tiles, 2-deep rotation
    f32x4  st_[2][4];     // scores in flight, 2 tiles: [parity][t*2+half]
    short8 pa[2];         // transposed P A-frags for current tile

    auto LK = [&](int kt, short8* d) {
        d[0] = *(const short8*)(kbase + (size_t)(kt * 32 + ql) * 32 + g * 8);
        d[1] = *(const short8*)(kbase + (size_t)(kt * 32 + 16 + ql) * 32 + g * 8);
    };
    auto LV = [&](int kt, short8* d) {
        d[0] = *(const short8*)(vbase + (size_t)ql * 512 + kt * 32 + 8 * g);
        d[1] = *(const short8*)(vbase + (size_t)(16 + ql) * 512 + kt * 32 + 8 * g);
    };
    auto S = [&](const short8* k, f32x4* st) {    // 4 score MFMAs
        st[0] = __builtin_amdgcn_mfma_f32_16x16x32_bf16(k[0], qf[0], z, 0, 0, 0);
        st[1] = __builtin_amdgcn_mfma_f32_16x16x32_bf16(k[1], qf[0], z, 0, 0, 0);
        st[2] = __builtin_amdgcn_mfma_f32_16x16x32_bf16(k[0], qf[1], z, 0, 0, 0);
        st[3] = __builtin_amdgcn_mfma_f32_16x16x32_bf16(k[1], qf[1], z, 0, 0, 0);
    };
    auto F = [&](int kt, const f32x4* st) {       // exp2+mask+pack+transpose
        #pragma unroll
        for (int t = 0; t < 2; ++t) {
            float p8[8];
            #pragma unroll
            for (int r = 0; r < 4; ++r) {
                p8[r]     = fexp2(st[t*2][r]);
                p8[4 + r] = fexp2(st[t*2+1][r]);
            }
            if (USE_MASK) {
                int dh = (kt >> 1) - qh[t]; dh = dh < 0 ? -dh : dh;
                if (dh <= 3) {
                    uint mm = (kt & 1) ? m1[t] : m0[t];
                    #pragma unroll
                    for (int i = 0; i < 8; ++i)
                        if ((mm >> i) & 1u) p8[i] = 0.f;
                }
            }
            uint Au = cvt_pk_bf16(p8[0], p8[1]);   // keys 4g+0,4g+1
            uint Bu = cvt_pk_bf16(p8[2], p8[3]);   // keys 4g+2,4g+3
            uint Cu = cvt_pk_bf16(p8[4], p8[5]);   // keys 16+4g+0,+1
            uint Du = cvt_pk_bf16(p8[6], p8[7]);   // keys 16+4g+2,+3
            asm("v_permlane32_swap_b32 %0, %1" : "+v"(Au), "+v"(Cu));
            asm("v_permlane32_swap_b32 %0, %1" : "+v"(Bu), "+v"(Du));
            union { uint u[4]; short8 s; } pk;
            pk.u[0] = Au; pk.u[1] = Bu; pk.u[2] = Cu; pk.u[3] = Du;
            pa[t] = pk.s;                           // A-frag in kappa key-order
        }
    };
    auto PV = [&](const short8* v) {
        #pragma unroll
        for (int t = 0; t < 2; ++t) {
            o0[t] = __builtin_amdgcn_mfma_f32_16x16x32_bf16(pa[t], v[0], o0[t], 0, 0, 0);
            o1[t] = __builtin_amdgcn_mfma_f32_16x16x32_bf16(pa[t], v[1], o1[t], 0, 0, 0);
            o2[t] = __builtin_amdgcn_mfma_f32_16x16x32_bf16(pa[t], onesf, o2[t], 0, 0, 0);
        }
    };

    // --- pipelined loop over 16 key-tiles ----------------------------------
    LK(0, kb_[0]); LK(1, kb_[1]); LK(2, kb_[2]);
    LV(0, vb_[0]); LV(1, vb_[1]);
    S(kb_[0], st_[0]);
    #pragma unroll
    for (int kt = 0; kt < 16; ++kt) {
        if (kt < 15) S(kb_[(kt + 1) % 3], st_[(kt + 1) & 1]);  // next scores
        if (kt < 13) LK(kt + 3, kb_[kt % 3]);                  // K 3 ahead
        F(kt, st_[kt & 1]);                                    // finish cur
        __builtin_amdgcn_s_setprio(1);
        PV(vb_[kt & 1]);                                       // PV cur
        __builtin_amdgcn_s_setprio(0);
        if (kt < 14) LV(kt + 2, vb_[kt & 1]);                  // V 2 ahead
    }

    ushort* op = att + (size_t)b * Ssz * Ed + h * 32;
    #pragma unroll
    for (int t = 0; t < 2; ++t) {
        #pragma unroll
        for (int r = 0; r < 4; ++r) {
            float iv = 1.f / o2[t][r];
            int row = qb + t * 16 + 4 * g + r;
            op[(size_t)row * Ed + ql]      = f2b(o0[t][r] * iv);
            op[(size_t)row * Ed + 16 + ql] = f2b(o1[t][r] * iv);
        }
    }
}

// ---------------------------------------------------------------------------
// channel LN on conv output C2[r=(b*4+ho)*64+w][co=256] -> out[b,co,ho,w]
__global__ __launch_bounds__(256) void ln_out_kernel(const float* __restrict__ C2,
                                                     const float* __restrict__ g,
                                                     const float* __restrict__ beta,
                                                     float* __restrict__ out) {
    __shared__ float lds[32 * 257];
    int w0 = blockIdx.x * 32, ho = blockIdx.y, b = blockIdx.z;
    int tid = threadIdx.x;
    size_t rbase = ((size_t)b * 4 + ho) * 64 + w0;

    for (int i = 0; i < 32; ++i)
        lds[i * 257 + tid] = C2[(rbase + i) * COd + tid];
    __syncthreads();

    int wv = tid >> 6, lane = tid & 63;
    for (int rr = 0; rr < 8; ++rr) {
        int i = wv * 8 + rr;
        float v0 = lds[i*257 + lane], v1 = lds[i*257 + lane + 64];
        float v2 = lds[i*257 + lane + 128], v3 = lds[i*257 + lane + 192];
        float s = v0 + v1 + v2 + v3;
        #pragma unroll
        for (int off = 32; off > 0; off >>= 1) s += __shfl_xor(s, off);
        float mu = s * (1.f / 256.f);
        float d0 = v0-mu, d1 = v1-mu, d2 = v2-mu, d3 = v3-mu;
        float qv = d0*d0 + d1*d1 + d2*d2 + d3*d3;
        #pragma unroll
        for (int off = 32; off > 0; off >>= 1) qv += __shfl_xor(qv, off);
        float rstd = rsqrtf(qv * (1.f / 256.f) + 1e-5f);
        lds[i*257 + lane]       = d0 * rstd * g[lane]       + beta[lane];
        lds[i*257 + lane + 64]  = d1 * rstd * g[lane + 64]  + beta[lane + 64];
        lds[i*257 + lane + 128] = d2 * rstd * g[lane + 128] + beta[lane + 128];
        lds[i*257 + lane + 192] = d3 * rstd * g[lane + 192] + beta[lane + 192];
    }
    __syncthreads();

    int w = tid & 31, half = tid >> 5;
    for (int j = 0; j < 32; ++j) {
        int co = half + j * 8;
        out[(((size_t)b * COd + co) * 4 + ho) * Wimg + w0 + w] = lds[w * 257 + co];
    }
}

// ---------------------------------------------------------------------------
extern "C" void kernel_launch(void* const* d_in, const int* in_sizes, int n_in,
                              void* d_out, int out_size, void* d_ws, size_t ws_size,
                              hipStream_t stream) {
    const float* image = (const float*)d_in[0];
    const float* in_w  = (const float*)d_in[1];
    const float* in_b  = (const float*)d_in[2];
    const float* out_w = (const float*)d_in[3];
    const float* out_b = (const float*)d_in[4];
    const float* ln1_g = (const float*)d_in[5];
    const float* ln1_b = (const float*)d_in[6];
    const float* ln2_g = (const float*)d_in[7];
    const float* ln2_b = (const float*)d_in[8];
    const float* w1    = (const float*)d_in[9];
    const float* b1    = (const float*)d_in[10];
    const float* w2    = (const float*)d_in[11];
    const float* b2    = (const float*)d_in[12];
    const float* convw = (const float*)d_in[13];
    const float* convb = (const float*)d_in[14];
    const float* mln_g = (const float*)d_in[15];
    const float* mln_b = (const float*)d_in[16];
    float* out = (float*)d_out;
    float* ws  = (float*)d_ws;

    // ws layout (float units):
    //  F1 (x1 stream fp32)   [0, 6291456)
    //  F2 (x3 stream fp32)   [6291456, 12582912)
    //  BIG [12582912, 28311552):
    //       QP bf16 @BIG | KP @+3145728 | VT @+6291456
    //       C2 f32 @BIG+4718592 (conv path, end)
    //  XNb  bf16 @ BIG+12582912  [25165824, 28311552)
    //  A2b  bf16 @ ws+25165824 (aliases dead XNb+ATTb at conv time)
    //  ATTb bf16 [28311552, 31457280)
    //  Wb   bf16 [31457280, 32858112)
    float* F1   = ws;
    float* F2   = ws + 6291456;
    float* BIG  = ws + 12582912;
    ushort* QP   = (ushort*)BIG;
    ushort* KP   = (ushort*)(BIG + 3145728);
    ushort* VT   = (ushort*)(BIG + 6291456);
    float*  C2   = BIG + 4718592;
    ushort* XNb  = (ushort*)(BIG + 12582912);
    ushort* A2b  = (ushort*)(ws + 25165824);
    ushort* ATTb = (ushort*)(ws + 28311552);
    ushort* Wb   = (ushort*)(ws + 31457280);

    ushort* in_wb  = Wb;                    // 663552
    ushort* out_wb = Wb + 663552;           // 221184
    ushort* w1b    = Wb + 884736;           // 884736
    ushort* w2b    = Wb + 1769472;          // 884736 (kappa k-order)
    ushort* cwb    = Wb + 2654208;          // 147456

    cvt_weights<<<(2801664 + 255) / 256, 256, 0, stream>>>(
        in_w, out_w, w1, w2, convw, Wb);

    // fused reshape + layer-0 LN1: image -> F1 (x1 fp32) + XNb (x1 bf16)
    reshape_ln<<<Bn * Himg, 256, 0, stream>>>(image, ln1_g, ln1_b, F1, XNb);

    for (int i = 0; i < Ld; ++i) {
        gemm_mfma<0,0,1,1><<<dim3(Mrows/128, 9), 256, 0, stream>>>(
            XNb, in_wb + (size_t)i * 3*Ed*Ed, in_b + i * 3*Ed,
            nullptr, nullptr, nullptr, QP, KP, VT, Mrows, 3*Ed, Ed);
        if (i >= 2) attn_mfma<1><<<dim3(Bn * NHd, 4), 256, 0, stream>>>(QP, KP, VT, ATTb);
        else        attn_mfma<0><<<dim3(Bn * NHd, 4), 256, 0, stream>>>(QP, KP, VT, ATTb);
        // out-proj + x1 + LN2 -> F2 (x3 fp32) + XNb (x3 bf16)
        gemm_ln<3><<<Mrows/64, 256, 0, stream>>>(
            ATTb, out_wb + (size_t)i * Ed*Ed, out_b + i*Ed,
            F1, ln2_g + i*Ed, ln2_b + i*Ed, F2, XNb);
        // fused MLP (mlp1 + relu + mlp2 + resid + epilogue), H in registers
        if (i < Ld - 1) {
            fused_mlp<1><<<Mrows/64, 256, 0, stream>>>(
                XNb, w1b + (size_t)i * 4*Ed*Ed, b1 + i * 4*Ed,
                w2b + (size_t)i * 4*Ed*Ed, b2 + i*Ed, F2,
                ln1_g + (i+1)*Ed, ln1_b + (i+1)*Ed, F1, XNb, nullptr);
        } else {
            fused_mlp<2><<<Mrows/64, 256, 0, stream>>>(
                XNb, w1b + (size_t)i * 4*Ed*Ed, b1 + i * 4*Ed,
                w2b + (size_t)i * 4*Ed*Ed, b2 + i*Ed, F2,
                nullptr, nullptr, nullptr, nullptr, A2b);
        }
    }

    gemm_mfma<0,0,0,0><<<dim3(16384/128, 4), 256, 0, stream>>>(
        A2b, cwb, convb, nullptr, C2, nullptr, nullptr, nullptr, nullptr,
        16384, COd, 576);
    ln_out_kernel<<<dim3(2, 4, Bn), 256, 0, stream>>>(C2, mln_g, mln_b, out);
}

// Round 11
// 906.685 us; speedup vs baseline: 1.6954x; 1.0206x over previous
//
#include <hip/hip_runtime.h>
#include <hip/hip_bf16.h>
#include <math.h>

// Problem constants
#define Bn   64
#define Ssz  512     // W*H = 64*8
#define Ed   192
#define NHd  6
#define HDd  32
#define Ld   6
#define COd  256
#define Himg 8
#define Wimg 64
#define Mrows (Bn*Ssz)   // 32768

typedef unsigned int  uint;
typedef unsigned short ushort;
using short8 = __attribute__((ext_vector_type(8))) short;
using f32x4  = __attribute__((ext_vector_type(4))) float;

__device__ inline ushort f2b(float f) {          // fp32 -> bf16 RNE
    uint u = __builtin_bit_cast(uint, f);
    u = (u + 0x7FFFu + ((u >> 16) & 1u)) >> 16;
    return (ushort)u;
}

__device__ __forceinline__ float fexp2(float x) {
#if __has_builtin(__builtin_amdgcn_exp2f)
    return __builtin_amdgcn_exp2f(x);
#else
    return exp2f(x);
#endif
}

// packed f32x2 -> bf16x2 (lo = a, hi = b); no builtin on gfx950, inline asm
__device__ __forceinline__ uint cvt_pk_bf16(float a, float b) {
    uint r;
    asm("v_cvt_pk_bf16_f32 %0, %1, %2" : "=v"(r) : "v"(a), "v"(b));
    return r;
}

// async global->LDS 16B: lane i lands at lds + i*16 (wave-uniform lds base)
__device__ __forceinline__ void gload16(const ushort* g, ushort* l, int lane) {
#if __has_builtin(__builtin_amdgcn_global_load_lds)
    __builtin_amdgcn_global_load_lds(
        (const __attribute__((address_space(1))) uint*)g,
        (__attribute__((address_space(3))) uint*)l, 16, 0, 0);
#else
    *(uint4*)(l + (size_t)lane * 8) = *(const uint4*)g;
#endif
}

// ---------------------------------------------------------------------------
// ALL weight conversions in one dispatch:
//   [0, 663552)        in_w   -> Wb
//   [663552, 884736)   out_w
//   [884736, 1769472)  w1
//   [1769472, 2654208) w2  (k-columns kappa-permuted: k ^= 12 when bit2^bit3,
//                           matching fused_mlp's register-transposed H slots)
//   [2654208, 2801664) conv_w (transposed to [co][kh*192+c])
__global__ __launch_bounds__(256) void cvt_weights(const float* __restrict__ in_w,
                                                   const float* __restrict__ out_w,
                                                   const float* __restrict__ w1,
                                                   const float* __restrict__ w2,
                                                   const float* __restrict__ convw,
                                                   ushort* __restrict__ Wb) {
    int t = blockIdx.x * 256 + threadIdx.x;
    if (t >= 2801664) return;
    float v;
    if (t < 663552)        v = in_w[t];
    else if (t < 884736)   v = out_w[t - 663552];
    else if (t < 1769472)  v = w1[t - 884736];
    else if (t < 2654208) {
        int u = t - 1769472;
        int k = u % 768;
        int ks = k ^ ((((k >> 2) ^ (k >> 3)) & 1) * 12);
        v = w2[u - k + ks];
    } else {
        int u = t - 2654208;
        int co = u / 576, rem = u % 576;
        int kh = rem / Ed, c = rem % Ed;
        v = convw[((size_t)co * Ed + c) * 3 + kh];
    }
    Wb[t] = f2b(v);
}

// ---------------------------------------------------------------------------
// FUSED reshape + layer-0 LN1: image [B,E,8,64] -> LN over E at rows
// s = w*8 + h -> F1 fp32 + XNb bf16.
__global__ __launch_bounds__(256) void reshape_ln(const float* __restrict__ img,
                                                  const float* __restrict__ g,
                                                  const float* __restrict__ bb,
                                                  float* __restrict__ outf,
                                                  ushort* __restrict__ outb) {
    __shared__ float lds[Ed * 65];               // 49920 B
    const int b = blockIdx.x >> 3, h = blockIdx.x & 7;
    const int tid = threadIdx.x;
    const float* src = img + ((size_t)b * Ed * Himg + h) * Wimg;  // +c*512+w
    #pragma unroll
    for (int i = 0; i < 48; ++i) {
        int idx = i * 256 + tid;
        int c = idx >> 6, w = idx & 63;
        lds[c * 65 + w] = src[(size_t)c * 512 + w];
    }
    __syncthreads();

    const int w = tid >> 2, q = tid & 3;         // 4 lanes per row w
    float vals[48];
    float s = 0.f;
    #pragma unroll
    for (int j = 0; j < 48; ++j) {
        vals[j] = lds[(q * 48 + j) * 65 + w];
        s += vals[j];
    }
    s += __shfl_xor(s, 1); s += __shfl_xor(s, 2);
    float mu = s * (1.f / 192.f);
    float qv = 0.f;
    #pragma unroll
    for (int j = 0; j < 48; ++j) { float d = vals[j] - mu; qv += d * d; }
    qv += __shfl_xor(qv, 1); qv += __shfl_xor(qv, 2);
    float rstd = rsqrtf(qv * (1.f / 192.f) + 1e-5f);

    size_t row = (size_t)b * Ssz + w * Himg + h;
    float*  of = outf + row * Ed + q * 48;
    ushort* ob = outb + row * Ed + q * 48;
    const float* gg = g + q * 48;
    const float* bv = bb + q * 48;
    #pragma unroll
    for (int j = 0; j < 48; ++j) {
        float y = (vals[j] - mu) * rstd * gg[j] + bv[j];
        of[j] = y;
        ob[j] = f2b(y);
    }
}

// ---------------------------------------------------------------------------
// bf16 MFMA GEMM: BM=128 BN=64 BK=96; 256 thr / 4 waves.
// VOUT: Q cols -> QP[bh][s][32] (pre-scaled by log2(e)/sqrt(hd)),
//       K cols -> KP[bh][s][32], V cols -> VT[bh][d][s'] (kappa order).
template<int RELU, int RESID, int OBF, int VOUT>
__global__ __launch_bounds__(256) void gemm_mfma(
    const ushort* __restrict__ A, const ushort* __restrict__ Wt,
    const float* __restrict__ bias, const float* __restrict__ resid,
    float* __restrict__ C, ushort* __restrict__ Cb,
    ushort* __restrict__ qpout, ushort* __restrict__ kpout,
    ushort* __restrict__ vtout,
    int M, int N, int K)
{
    __shared__ __align__(16) ushort As[12288];   // 24 frags (8 msub x 3 ksub) * 1KB
    __shared__ __align__(16) ushort Bs[6144];    // 12 frags (4 nsub x 3 ksub) * 1KB
    const int tid  = threadIdx.x;
    const int lane = tid & 63;
    const int wave = tid >> 6;
    const int wr = wave >> 1, wc = wave & 1;
    const int bm = blockIdx.x * 128;
    const int bn = blockIdx.y * 64;

    const ushort* Ag[6]; ushort* Al[6];
    #pragma unroll
    for (int i = 0; i < 6; ++i) {
        int fa = 4 * i + wave;                 // 0..23
        int msub = fa / 3, ksub = fa % 3;
        int m = msub * 16 + (lane & 15);
        int k = ksub * 32 + ((lane >> 4) << 3);
        Ag[i] = A + (size_t)(bm + m) * K + k;
        Al[i] = As + fa * 512;                 // wave-uniform
    }
    const ushort* Bg[3]; ushort* Bl[3];
    #pragma unroll
    for (int i = 0; i < 3; ++i) {
        int fb = 4 * i + wave;                 // 0..11
        int nsub = fb / 3, ksub = fb % 3;
        int n = nsub * 16 + (lane & 15);
        int k = ksub * 32 + ((lane >> 4) << 3);
        Bg[i] = Wt + (size_t)(bn + n) * K + k;
        Bl[i] = Bs + fb * 512;
    }

    f32x4 acc[4][2];
    #pragma unroll
    for (int i = 0; i < 4; ++i)
        #pragma unroll
        for (int j = 0; j < 2; ++j) acc[i][j] = (f32x4){0.f, 0.f, 0.f, 0.f};

    for (int k0 = 0; k0 < K; k0 += 96) {
        #pragma unroll
        for (int i = 0; i < 6; ++i) gload16(Ag[i] + k0, Al[i], lane);
        #pragma unroll
        for (int i = 0; i < 3; ++i) gload16(Bg[i] + k0, Bl[i], lane);
        __syncthreads();
        #pragma unroll
        for (int ksub = 0; ksub < 3; ++ksub) {
            short8 af[4], bf[2];
            #pragma unroll
            for (int ms = 0; ms < 4; ++ms)
                af[ms] = *(const short8*)(As + (((wr*4+ms)*3 + ksub) * 64 + lane) * 8);
            #pragma unroll
            for (int ns = 0; ns < 2; ++ns)
                bf[ns] = *(const short8*)(Bs + (((wc*2+ns)*3 + ksub) * 64 + lane) * 8);
            #pragma unroll
            for (int ms = 0; ms < 4; ++ms)
                #pragma unroll
                for (int ns = 0; ns < 2; ++ns)
                    acc[ms][ns] = __builtin_amdgcn_mfma_f32_16x16x32_bf16(
                        af[ms], bf[ns], acc[ms][ns], 0, 0, 0);
        }
        __syncthreads();
    }

    int q = lane >> 4, colL = lane & 15;
    #pragma unroll
    for (int ms = 0; ms < 4; ++ms) {
        #pragma unroll
        for (int ns = 0; ns < 2; ++ns) {
            int row0 = bm + (wr*4 + ms) * 16 + q * 4;
            int col  = bn + (wc*2 + ns) * 16 + colL;
            float bvv = bias[col];
            float v[4];
            #pragma unroll
            for (int r = 0; r < 4; ++r) {
                v[r] = acc[ms][ns][r] + bvv;
                if (RELU) v[r] = fmaxf(v[r], 0.f);
                if (RESID) v[r] += resid[(size_t)(row0 + r) * N + col];
            }
            if (VOUT) {
                int bidx = row0 >> 9, srow = row0 & 511;
                if (col >= 384) {                 // V -> VT[bh][d][s'] (kappa)
                    int hh = (col - 384) >> 5, dd = (col - 384) & 31;
                    int sr = srow ^ ((((srow >> 2) ^ (srow >> 3)) & 1) * 12);
                    ushort4 pv;
                    pv.x = f2b(v[0]); pv.y = f2b(v[1]); pv.z = f2b(v[2]); pv.w = f2b(v[3]);
                    *(ushort4*)(vtout + (((size_t)(bidx * NHd + hh) * 32 + dd) << 9) + sr) = pv;
                } else {                          // Q/K -> {QP,KP}[bh][s][32]
                    ushort* dst = (col < 192) ? qpout : kpout;
                    int cc = (col < 192) ? col : col - 192;
                    if (col < 192) {              // fold log2(e)/sqrt(32) into Q
                        const float c2 = 0.2550547270628364f;
                        #pragma unroll
                        for (int r = 0; r < 4; ++r) v[r] *= c2;
                    }
                    int hh = cc >> 5, dd = cc & 31;
                    ushort* p = dst + ((size_t)(bidx * NHd + hh) << 14) + (size_t)srow * 32 + dd;
                    p[0]  = f2b(v[0]); p[32] = f2b(v[1]);
                    p[64] = f2b(v[2]); p[96] = f2b(v[3]);
                }
            } else {
                #pragma unroll
                for (int r = 0; r < 4; ++r) {
                    if (OBF) Cb[(size_t)(row0 + r) * N + col] = f2b(v[r]);
                    else     C [(size_t)(row0 + r) * N + col] = v[r];
                }
            }
        }
    }
}

// ---------------------------------------------------------------------------
// Fused GEMM (+bias +resid) + row-LN. N=192 fixed. Used for out-proj only.
// BM=64, BN=192, BK=64, 256 thr / 4 waves. K = KIT*64.
template<int KIT>
__global__ __launch_bounds__(256) void gemm_ln(
    const ushort* __restrict__ A, const ushort* __restrict__ Wt,
    const float* __restrict__ bias, const float* __restrict__ resid,
    const float* __restrict__ lng, const float* __restrict__ lnb,
    float* __restrict__ outf, ushort* __restrict__ outb)
{
    __shared__ __align__(16) ushort As[4096];    // 8 frags (4 msub x 2 ksub)
    __shared__ __align__(16) ushort Bs[12288];   // 24 frags (12 nsub x 2 ksub)
    const int K = KIT * 64;
    const int lane = threadIdx.x & 63;
    const int wave = threadIdx.x >> 6;
    const int g = lane >> 4, ql = lane & 15;
    const int bm = blockIdx.x * 64;

    const ushort* Gp[8]; ushort* Lp[8];
    #pragma unroll
    for (int i = 0; i < 8; ++i) {
        int f = 4 * i + wave;                    // 0..31
        if (f < 8) {
            int msub = f >> 1, ksub = f & 1;
            Gp[i] = A + (size_t)(bm + msub * 16 + ql) * K + ksub * 32 + g * 8;
            Lp[i] = As + f * 512;
        } else {
            int fb = f - 8, nsub = fb >> 1, ksub = fb & 1;
            Gp[i] = Wt + (size_t)(nsub * 16 + ql) * K + ksub * 32 + g * 8;
            Lp[i] = Bs + fb * 512;
        }
    }

    f32x4 acc[12];
    #pragma unroll
    for (int i = 0; i < 12; ++i) acc[i] = (f32x4){0.f, 0.f, 0.f, 0.f};

    for (int kc = 0; kc < KIT; ++kc) {
        #pragma unroll
        for (int i = 0; i < 8; ++i) gload16(Gp[i] + kc * 64, Lp[i], lane);
        __syncthreads();
        #pragma unroll
        for (int ksub = 0; ksub < 2; ++ksub) {
            short8 af = *(const short8*)(As + ((wave * 2 + ksub) * 64 + lane) * 8);
            #pragma unroll
            for (int ns = 0; ns < 12; ++ns) {
                short8 bf = *(const short8*)(Bs + ((ns * 2 + ksub) * 64 + lane) * 8);
                acc[ns] = __builtin_amdgcn_mfma_f32_16x16x32_bf16(af, bf, acc[ns], 0, 0, 0);
            }
        }
        __syncthreads();
    }

    float bi[12], gg[12], bb[12];
    #pragma unroll
    for (int ns = 0; ns < 12; ++ns) {
        int col = ns * 16 + ql;
        bi[ns] = bias[col];
        gg[ns] = lng[col]; bb[ns] = lnb[col];
    }
    #pragma unroll
    for (int r = 0; r < 4; ++r) {
        int row = bm + wave * 16 + g * 4 + r;
        float v[12];
        #pragma unroll
        for (int ns = 0; ns < 12; ++ns)
            v[ns] = acc[ns][r] + bi[ns] + resid[(size_t)row * Ed + ns * 16 + ql];
        float s = 0.f;
        #pragma unroll
        for (int ns = 0; ns < 12; ++ns) s += v[ns];
        s += __shfl_xor(s, 1); s += __shfl_xor(s, 2);
        s += __shfl_xor(s, 4); s += __shfl_xor(s, 8);
        float mu = s * (1.f / 192.f);
        float qv = 0.f;
        #pragma unroll
        for (int ns = 0; ns < 12; ++ns) { float d = v[ns] - mu; qv += d * d; }
        qv += __shfl_xor(qv, 1); qv += __shfl_xor(qv, 2);
        qv += __shfl_xor(qv, 4); qv += __shfl_xor(qv, 8);
        float rstd = rsqrtf(qv * (1.f / 192.f) + 1e-5f);
        #pragma unroll
        for (int ns = 0; ns < 12; ++ns) {
            float y = (v[ns] - mu) * rstd * gg[ns] + bb[ns];
            int col = ns * 16 + ql;
            outf[(size_t)row * Ed + col] = y;
            outb[(size_t)row * Ed + col] = f2b(y);
        }
    }
}

// ---------------------------------------------------------------------------
// FUSED MLP v4: Y = relu(X@W1^T + b1)@W2k^T + b2 + resid, then epilogue.
// v2/v3 plateaued ~54-56 us with MfmaUtil ~13% regardless of TLP or pipeline
// depth -> theory: all 512 blocks fetch the SAME 24KB weight chunk through
// L2 in barrier-lockstep (12.3 MB redundant L2 traffic per chunk-step);
// congestion latency dominates. v4 halves the redundancy: BM=128, 8 waves,
// 512 threads, grid 256 -- each staged chunk serves 128 rows. Schedule is
// v3's (3 LDS buffers, P1 one chunk ahead); each wave stages 3 frags.
// MODE=1: LN epilogue. MODE=2: conv-im2col bf16 scatter.
template<int MODE>
__global__ __launch_bounds__(512) void fused_mlp(
    const ushort* __restrict__ X, const ushort* __restrict__ W1,
    const float* __restrict__ b1, const ushort* __restrict__ W2k,
    const float* __restrict__ b2, const float* __restrict__ resid,
    const float* __restrict__ lng, const float* __restrict__ lnb,
    float* __restrict__ outf, ushort* __restrict__ outb,
    ushort* __restrict__ a2out)
{
    __shared__ __align__(16) ushort Ws[3][24][512];   // 72 KB
    const int lane = threadIdx.x & 63;
    const int wave = threadIdx.x >> 6;           // 0..7
    const int g = lane >> 4, ql = lane & 15;
    const int bm = blockIdx.x * 128;
    const int row16 = bm + wave * 16;            // this wave's 16 rows
    const f32x4 z = {0.f,0.f,0.f,0.f};

    short8 xf[6];                                // X B-frags: row=ql, k=g*8
    #pragma unroll
    for (int ks = 0; ks < 6; ++ks)
        xf[ks] = *(const short8*)(X + (size_t)(row16 + ql) * Ed + ks * 32 + g * 8);

    // staging: 3 frags per wave: f = wave*3 + i.  f<12: W1 (hsub=f/6,
    // ksub=f%6), chunk stride 32*Ed; f>=12: W2 (n2=f-12), chunk stride 32.
    const ushort* gsrc[3]; ushort* ldst[3]; int strd[3];
    #pragma unroll
    for (int i = 0; i < 3; ++i) {
        int f = wave * 3 + i;
        if (f < 12) {
            int hsub = f / 6, ksub = f % 6;
            gsrc[i] = W1 + (size_t)(hsub * 16 + ql) * Ed + ksub * 32 + g * 8;
            strd[i] = 32 * Ed;
        } else {
            int n2 = f - 12;
            gsrc[i] = W2k + (size_t)(n2 * 16 + ql) * 768 + g * 8;
            strd[i] = 32;
        }
        ldst[i] = &Ws[0][f][0];
    }
    auto STAGE = [&](int c) {
        int b = c % 3;
        #pragma unroll
        for (int i = 0; i < 3; ++i)
            gload16(gsrc[i] + (size_t)c * strd[i], ldst[i] + b * 12288, lane);
    };

    f32x4 yacc[12];
    #pragma unroll
    for (int i = 0; i < 12; ++i) yacc[i] = z;

    f32x4 st_[2][2];                             // scores, 2 chunks in flight

    auto P1 = [&](int c) {                       // 12 MFMAs -> st_[c&1]
        const ushort* wb = &Ws[c % 3][0][0];
        f32x4 s0 = z, s1 = z;
        #pragma unroll
        for (int ks = 0; ks < 6; ++ks) {
            short8 a0 = *(const short8*)(wb + (size_t)ks * 512 + lane * 8);
            short8 a1 = *(const short8*)(wb + (size_t)(6 + ks) * 512 + lane * 8);
            s0 = __builtin_amdgcn_mfma_f32_16x16x32_bf16(a0, xf[ks], s0, 0, 0, 0);
            s1 = __builtin_amdgcn_mfma_f32_16x16x32_bf16(a1, xf[ks], s1, 0, 0, 0);
        }
        st_[c & 1][0] = s0; st_[c & 1][1] = s1;
    };
    auto PACK = [&](int c) -> short8 {           // bias+relu+pack+transpose
        float4 bA = *(const float4*)(b1 + c * 32 + 4 * g);
        float4 bB = *(const float4*)(b1 + c * 32 + 16 + 4 * g);
        const f32x4 s0 = st_[c & 1][0], s1 = st_[c & 1][1];
        float p8[8];
        p8[0] = fmaxf(s0[0] + bA.x, 0.f);
        p8[1] = fmaxf(s0[1] + bA.y, 0.f);
        p8[2] = fmaxf(s0[2] + bA.z, 0.f);
        p8[3] = fmaxf(s0[3] + bA.w, 0.f);
        p8[4] = fmaxf(s1[0] + bB.x, 0.f);
        p8[5] = fmaxf(s1[1] + bB.y, 0.f);
        p8[6] = fmaxf(s1[2] + bB.z, 0.f);
        p8[7] = fmaxf(s1[3] + bB.w, 0.f);
        uint Au = cvt_pk_bf16(p8[0], p8[1]);
        uint Bu = cvt_pk_bf16(p8[2], p8[3]);
        uint Cu = cvt_pk_bf16(p8[4], p8[5]);
        uint Du = cvt_pk_bf16(p8[6], p8[7]);
        asm("v_permlane32_swap_b32 %0, %1" : "+v"(Au), "+v"(Cu));
        asm("v_permlane32_swap_b32 %0, %1" : "+v"(Bu), "+v"(Du));
        union { uint u[4]; short8 s; } pk;
        pk.u[0] = Au; pk.u[1] = Bu; pk.u[2] = Cu; pk.u[3] = Du;
        return pk.s;                             // H A-frag, kappa slot order
    };
    auto P2 = [&](int c, short8 pa) {            // 12 MFMAs -> yacc
        const ushort* wb = &Ws[c % 3][0][0];
        #pragma unroll
        for (int n2 = 0; n2 < 12; ++n2) {
            short8 bfr = *(const short8*)(wb + (size_t)(12 + n2) * 512 + lane * 8);
            yacc[n2] = __builtin_amdgcn_mfma_f32_16x16x32_bf16(pa, bfr, yacc[n2], 0, 0, 0);
        }
    };

    STAGE(0); STAGE(1);
    __syncthreads();                             // buf0, buf1 ready
    P1(0);
    #pragma unroll
    for (int c = 0; c < 24; ++c) {
        if (c > 0) __syncthreads();              // buf c+1 ready; buf (c+2)%3 free
        if (c < 22) STAGE(c + 2);
        if (c < 23) P1(c + 1);
        short8 pa = PACK(c);
        __builtin_amdgcn_s_setprio(1);
        P2(c, pa);
        __builtin_amdgcn_s_setprio(0);
    }

    // epilogue (gemm_ln layout: row = row16 + g*4 + r, col = ns*16 + ql)
    float bi[12], gg[12], bb[12];
    #pragma unroll
    for (int ns = 0; ns < 12; ++ns) {
        int col = ns * 16 + ql;
        bi[ns] = b2[col];
        if (MODE == 1) { gg[ns] = lng[col]; bb[ns] = lnb[col]; }
    }
    #pragma unroll
    for (int r = 0; r < 4; ++r) {
        int row = row16 + g * 4 + r;
        float v[12];
        #pragma unroll
        for (int ns = 0; ns < 12; ++ns)
            v[ns] = yacc[ns][r] + bi[ns] + resid[(size_t)row * Ed + ns * 16 + ql];
        if (MODE == 1) {
            float s = 0.f;
            #pragma unroll
            for (int ns = 0; ns < 12; ++ns) s += v[ns];
            s += __shfl_xor(s, 1); s += __shfl_xor(s, 2);
            s += __shfl_xor(s, 4); s += __shfl_xor(s, 8);
            float mu = s * (1.f / 192.f);
            float qv = 0.f;
            #pragma unroll
            for (int ns = 0; ns < 12; ++ns) { float d = v[ns] - mu; qv += d * d; }
            qv += __shfl_xor(qv, 1); qv += __shfl_xor(qv, 2);
            qv += __shfl_xor(qv, 4); qv += __shfl_xor(qv, 8);
            float rstd = rsqrtf(qv * (1.f / 192.f) + 1e-5f);
            #pragma unroll
            for (int ns = 0; ns < 12; ++ns) {
                float y = (v[ns] - mu) * rstd * gg[ns] + bb[ns];
                int col = ns * 16 + ql;
                outf[(size_t)row * Ed + col] = y;
                outb[(size_t)row * Ed + col] = f2b(y);
            }
        } else {
            int bz = row >> 9, s = row & 511;
            int w = s >> 3, h = s & 7;
            #pragma unroll
            for (int ho = 0; ho < 4; ++ho) {
                int kh = h + 1 - 2 * ho;
                if (kh >= 0 && kh < 3) {
                    size_t r2 = ((size_t)((bz * 4 + ho) * 64 + w)) * 576 + kh * 192;
                    #pragma unroll
                    for (int ns = 0; ns < 12; ++ns)
                        a2out[r2 + ns * 16 + ql] = f2b(v[ns]);
                }
            }
            if (h == 0) {                       // top pad: hin = -1 stripe
                size_t r2 = ((size_t)(bz * 4 * 64 + w)) * 576;   // ho=0, kh=0
                #pragma unroll
                for (int ns = 0; ns < 12; ++ns)
                    a2out[r2 + ns * 16 + ql] = 0;
            }
        }
    }
}

// ---------------------------------------------------------------------------
// MFMA attention (round-5 best: 41.3 us), 2 q-tiles per wave (32 q x 512
// keys), LDS-free with in-register P transpose. Score stage pipelined one
// tile deep; K 3-deep, V 2-deep prefetch. grid (384 bh, 4); 4 waves.
template<int USE_MASK>
__global__ __launch_bounds__(256) void attn_mfma(const ushort* __restrict__ qp,
                                                 const ushort* __restrict__ kp,
                                                 const ushort* __restrict__ vt,
                                                 ushort* __restrict__ att) {
    const int bh = blockIdx.x;
    const int b = bh / NHd, h = bh % NHd;
    const int wave = threadIdx.x >> 6, lane = threadIdx.x & 63;
    const int g = lane >> 4, ql = lane & 15;
    const int qb = blockIdx.y * 128 + wave * 32;

    const ushort* qbase = qp + ((size_t)bh << 14);
    const ushort* kbase = kp + ((size_t)bh << 14);
    const ushort* vbase = vt + ((size_t)bh << 14);
    short8 qf[2];
    #pragma unroll
    for (int t = 0; t < 2; ++t)
        qf[t] = *(const short8*)(qbase + (size_t)(qb + t * 16 + ql) * 32 + g * 8);

    short8 onesf;
    #pragma unroll
    for (int j = 0; j < 8; ++j) onesf[j] = (short)0x3F80;   // bf16 1.0

    uint m0[2], m1[2]; int qh[2];
    if (USE_MASK) {
        #pragma unroll
        for (int t = 0; t < 2; ++t) {
            int qwt = ((qb + t * 16) & 63) + ql;      // no wrap: base%16==0
            qh[t] = (qb + t * 16) >> 6;
            uint a0 = 0, a1 = 0;
            #pragma unroll
            for (int i = 0; i < 8; ++i) {
                int keyl = (i >> 2) * 16 + 4 * g + (i & 3);
                int d0 = keyl - qwt;      d0 = d0 < 0 ? -d0 : d0;
                int d1 = keyl + 32 - qwt; d1 = d1 < 0 ? -d1 : d1;
                if (d0 <= 5) a0 |= (1u << i);
                if (d1 <= 5) a1 |= (1u << i);
            }
            m0[t] = a0; m1[t] = a1;
        }
    }

    f32x4 o0[2], o1[2], o2[2];
    #pragma unroll
    for (int t = 0; t < 2; ++t) {
        o0[t] = (f32x4){0.f,0.f,0.f,0.f};
        o1[t] = (f32x4){0.f,0.f,0.f,0.f};
        o2[t] = (f32x4){0.f,0.f,0.f,0.f};
    }
    const f32x4 z = {0.f,0.f,0.f,0.f};

    short8 kb_[3][2];     // K tiles, 3-deep rotation
    short8 vb_[2][2];     // V tiles, 2-deep rotation
    f32x4  st_[2][4];     // scores in flight, 2 tiles: [parity][t*2+half]
    short8 pa[2];         // transposed P A-frags for current tile

    auto LK = [&](int kt, short8* d) {
        d[0] = *(const short8*)(kbase + (size_t)(kt * 32 + ql) * 32 + g * 8);
        d[1] = *(const short8*)(kbase + (size_t)(kt * 32 + 16 + ql) * 32 + g * 8);
    };
    auto LV = [&](int kt, short8* d) {
        d[0] = *(const short8*)(vbase + (size_t)ql * 512 + kt * 32 + 8 * g);
        d[1] = *(const short8*)(vbase + (size_t)(16 + ql) * 512 + kt * 32 + 8 * g);
    };
    auto S = [&](const short8* k, f32x4* st) {    // 4 score MFMAs
        st[0] = __builtin_amdgcn_mfma_f32_16x16x32_bf16(k[0], qf[0], z, 0, 0, 0);
        st[1] = __builtin_amdgcn_mfma_f32_16x16x32_bf16(k[1], qf[0], z, 0, 0, 0);
        st[2] = __builtin_amdgcn_mfma_f32_16x16x32_bf16(k[0], qf[1], z, 0, 0, 0);
        st[3] = __builtin_amdgcn_mfma_f32_16x16x32_bf16(k[1], qf[1], z, 0, 0, 0);
    };
    auto F = [&](int kt, const f32x4* st) {       // exp2+mask+pack+transpose
        #pragma unroll
        for (int t = 0; t < 2; ++t) {
            float p8[8];
            #pragma unroll
            for (int r = 0; r < 4; ++r) {
                p8[r]     = fexp2(st[t*2][r]);
                p8[4 + r] = fexp2(st[t*2+1][r]);
            }
            if (USE_MASK) {
                int dh = (kt >> 1) - qh[t]; dh = dh < 0 ? -dh : dh;
                if (dh <= 3) {
                    uint mm = (kt & 1) ? m1[t] : m0[t];
                    #pragma unroll
                    for (int i = 0; i < 8; ++i)
                        if ((mm >> i) & 1u) p8[i] = 0.f;
                }
            }
            uint Au = cvt_pk_bf16(p8[0], p8[1]);   // keys 4g+0,4g+1
            uint Bu = cvt_pk_bf16(p8[2], p8[3]);   // keys 4g+2,4g+3
            uint Cu = cvt_pk_bf16(p8[4], p8[5]);   // keys 16+4g+0,+1
            uint Du = cvt_pk_bf16(p8[6], p8[7]);   // keys 16+4g+2,+3
            asm("v_permlane32_swap_b32 %0, %1" : "+v"(Au), "+v"(Cu));
            asm("v_permlane32_swap_b32 %0, %1" : "+v"(Bu), "+v"(Du));
            union { uint u[4]; short8 s; } pk;
            pk.u[0] = Au; pk.u[1] = Bu; pk.u[2] = Cu; pk.u[3] = Du;
            pa[t] = pk.s;                           // A-frag in kappa key-order
        }
    };
    auto PV = [&](const short8* v) {
        #pragma unroll
        for (int t = 0; t < 2; ++t) {
            o0[t] = __builtin_amdgcn_mfma_f32_16x16x32_bf16(pa[t], v[0], o0[t], 0, 0, 0);
            o1[t] = __builtin_amdgcn_mfma_f32_16x16x32_bf16(pa[t], v[1], o1[t], 0, 0, 0);
            o2[t] = __builtin_amdgcn_mfma_f32_16x16x32_bf16(pa[t], onesf, o2[t], 0, 0, 0);
        }
    };

    // --- pipelined loop over 16 key-tiles ----------------------------------
    LK(0, kb_[0]); LK(1, kb_[1]); LK(2, kb_[2]);
    LV(0, vb_[0]); LV(1, vb_[1]);
    S(kb_[0], st_[0]);
    #pragma unroll
    for (int kt = 0; kt < 16; ++kt) {
        if (kt < 15) S(kb_[(kt + 1) % 3], st_[(kt + 1) & 1]);  // next scores
        if (kt < 13) LK(kt + 3, kb_[kt % 3]);                  // K 3 ahead
        F(kt, st_[kt & 1]);                                    // finish cur
        __builtin_amdgcn_s_setprio(1);
        PV(vb_[kt & 1]);                                       // PV cur
        __builtin_amdgcn_s_setprio(0);
        if (kt < 14) LV(kt + 2, vb_[kt & 1]);                  // V 2 ahead
    }

    ushort* op = att + (size_t)b * Ssz * Ed + h * 32;
    #pragma unroll
    for (int t = 0; t < 2; ++t) {
        #pragma unroll
        for (int r = 0; r < 4; ++r) {
            float iv = 1.f / o2[t][r];
            int row = qb + t * 16 + 4 * g + r;
            op[(size_t)row * Ed + ql]      = f2b(o0[t][r] * iv);
            op[(size_t)row * Ed + 16 + ql] = f2b(o1[t][r] * iv);
        }
    }
}

// ---------------------------------------------------------------------------
// channel LN on conv output C2[r=(b*4+ho)*64+w][co=256] -> out[b,co,ho,w]
__global__ __launch_bounds__(256) void ln_out_kernel(const float* __restrict__ C2,
                                                     const float* __restrict__ g,
                                                     const float* __restrict__ beta,
                                                     float* __restrict__ out) {
    __shared__ float lds[32 * 257];
    int w0 = blockIdx.x * 32, ho = blockIdx.y, b = blockIdx.z;
    int tid = threadIdx.x;
    size_t rbase = ((size_t)b * 4 + ho) * 64 + w0;

    for (int i = 0; i < 32; ++i)
        lds[i * 257 + tid] = C2[(rbase + i) * COd + tid];
    __syncthreads();

    int wv = tid >> 6, lane = tid & 63;
    for (int rr = 0; rr < 8; ++rr) {
        int i = wv * 8 + rr;
        float v0 = lds[i*257 + lane], v1 = lds[i*257 + lane + 64];
        float v2 = lds[i*257 + lane + 128], v3 = lds[i*257 + lane + 192];
        float s = v0 + v1 + v2 + v3;
        #pragma unroll
        for (int off = 32; off > 0; off >>= 1) s += __shfl_xor(s, off);
        float mu = s * (1.f / 256.f);
        float d0 = v0-mu, d1 = v1-mu, d2 = v2-mu, d3 = v3-mu;
        float qv = d0*d0 + d1*d1 + d2*d2 + d3*d3;
        #pragma unroll
        for (int off = 32; off > 0; off >>= 1) qv += __shfl_xor(qv, off);
        float rstd = rsqrtf(qv * (1.f / 256.f) + 1e-5f);
        lds[i*257 + lane]       = d0 * rstd * g[lane]       + beta[lane];
        lds[i*257 + lane + 64]  = d1 * rstd * g[lane + 64]  + beta[lane + 64];
        lds[i*257 + lane + 128] = d2 * rstd * g[lane + 128] + beta[lane + 128];
        lds[i*257 + lane + 192] = d3 * rstd * g[lane + 192] + beta[lane + 192];
    }
    __syncthreads();

    int w = tid & 31, half = tid >> 5;
    for (int j = 0; j < 32; ++j) {
        int co = half + j * 8;
        out[(((size_t)b * COd + co) * 4 + ho) * Wimg + w0 + w] = lds[w * 257 + co];
    }
}

// ---------------------------------------------------------------------------
extern "C" void kernel_launch(void* const* d_in, const int* in_sizes, int n_in,
                              void* d_out, int out_size, void* d_ws, size_t ws_size,
                              hipStream_t stream) {
    const float* image = (const float*)d_in[0];
    const float* in_w  = (const float*)d_in[1];
    const float* in_b  = (const float*)d_in[2];
    const float* out_w = (const float*)d_in[3];
    const float* out_b = (const float*)d_in[4];
    const float* ln1_g = (const float*)d_in[5];
    const float* ln1_b = (const float*)d_in[6];
    const float* ln2_g = (const float*)d_in[7];
    const float* ln2_b = (const float*)d_in[8];
    const float* w1    = (const float*)d_in[9];
    const float* b1    = (const float*)d_in[10];
    const float* w2    = (const float*)d_in[11];
    const float* b2    = (const float*)d_in[12];
    const float* convw = (const float*)d_in[13];
    const float* convb = (const float*)d_in[14];
    const float* mln_g = (const float*)d_in[15];
    const float* mln_b = (const float*)d_in[16];
    float* out = (float*)d_out;
    float* ws  = (float*)d_ws;

    // ws layout (float units):
    //  F1 (x1 stream fp32)   [0, 6291456)
    //  F2 (x3 stream fp32)   [6291456, 12582912)
    //  BIG [12582912, 28311552):
    //       QP bf16 @BIG | KP @+3145728 | VT @+6291456
    //       C2 f32 @BIG+4718592 (conv path, end)
    //  XNb  bf16 @ BIG+12582912  [25165824, 28311552)
    //  A2b  bf16 @ ws+25165824 (aliases dead XNb+ATTb at conv time)
    //  ATTb bf16 [28311552, 31457280)
    //  Wb   bf16 [31457280, 32858112)
    float* F1   = ws;
    float* F2   = ws + 6291456;
    float* BIG  = ws + 12582912;
    ushort* QP   = (ushort*)BIG;
    ushort* KP   = (ushort*)(BIG + 3145728);
    ushort* VT   = (ushort*)(BIG + 6291456);
    float*  C2   = BIG + 4718592;
    ushort* XNb  = (ushort*)(BIG + 12582912);
    ushort* A2b  = (ushort*)(ws + 25165824);
    ushort* ATTb = (ushort*)(ws + 28311552);
    ushort* Wb   = (ushort*)(ws + 31457280);

    ushort* in_wb  = Wb;                    // 663552
    ushort* out_wb = Wb + 663552;           // 221184
    ushort* w1b    = Wb + 884736;           // 884736
    ushort* w2b    = Wb + 1769472;          // 884736 (kappa k-order)
    ushort* cwb    = Wb + 2654208;          // 147456

    cvt_weights<<<(2801664 + 255) / 256, 256, 0, stream>>>(
        in_w, out_w, w1, w2, convw, Wb);

    // fused reshape + layer-0 LN1: image -> F1 (x1 fp32) + XNb (x1 bf16)
    reshape_ln<<<Bn * Himg, 256, 0, stream>>>(image, ln1_g, ln1_b, F1, XNb);

    for (int i = 0; i < Ld; ++i) {
        gemm_mfma<0,0,1,1><<<dim3(Mrows/128, 9), 256, 0, stream>>>(
            XNb, in_wb + (size_t)i * 3*Ed*Ed, in_b + i * 3*Ed,
            nullptr, nullptr, nullptr, QP, KP, VT, Mrows, 3*Ed, Ed);
        if (i >= 2) attn_mfma<1><<<dim3(Bn * NHd, 4), 256, 0, stream>>>(QP, KP, VT, ATTb);
        else        attn_mfma<0><<<dim3(Bn * NHd, 4), 256, 0, stream>>>(QP, KP, VT, ATTb);
        // out-proj + x1 + LN2 -> F2 (x3 fp32) + XNb (x3 bf16)
        gemm_ln<3><<<Mrows/64, 256, 0, stream>>>(
            ATTb, out_wb + (size_t)i * Ed*Ed, out_b + i*Ed,
            F1, ln2_g + i*Ed, ln2_b + i*Ed, F2, XNb);
        // fused MLP (mlp1 + relu + mlp2 + resid + epilogue), H in registers
        if (i < Ld - 1) {
            fused_mlp<1><<<Mrows/128, 512, 0, stream>>>(
                XNb, w1b + (size_t)i * 4*Ed*Ed, b1 + i * 4*Ed,
                w2b + (size_t)i * 4*Ed*Ed, b2 + i*Ed, F2,
                ln1_g + (i+1)*Ed, ln1_b + (i+1)*Ed, F1, XNb, nullptr);
        } else {
            fused_mlp<2><<<Mrows/128, 512, 0, stream>>>(
                XNb, w1b + (size_t)i * 4*Ed*Ed, b1 + i * 4*Ed,
                w2b + (size_t)i * 4*Ed*Ed, b2 + i*Ed, F2,
                nullptr, nullptr, nullptr, nullptr, A2b);
        }
    }

    gemm_mfma<0,0,0,0><<<dim3(16384/128, 4), 256, 0, stream>>>(
        A2b, cwb, convb, nullptr, C2, nullptr, nullptr, nullptr, nullptr,
        16384, COd, 576);
    ln_out_kernel<<<dim3(2, 4, Bn), 256, 0, stream>>>(C2, mln_g, mln_b, out);
}

// Round 12
// 898.419 us; speedup vs baseline: 1.7110x; 1.0092x over previous
//
#include <hip/hip_runtime.h>
#include <hip/hip_bf16.h>
#include <math.h>

// Problem constants
#define Bn   64
#define Ssz  512     // W*H = 64*8
#define Ed   192
#define NHd  6
#define HDd  32
#define Ld   6
#define COd  256
#define Himg 8
#define Wimg 64
#define Mrows (Bn*Ssz)   // 32768

typedef unsigned int  uint;
typedef unsigned short ushort;
using short8 = __attribute__((ext_vector_type(8))) short;
using f32x4  = __attribute__((ext_vector_type(4))) float;

__device__ inline ushort f2b(float f) {          // fp32 -> bf16 RNE
    uint u = __builtin_bit_cast(uint, f);
    u = (u + 0x7FFFu + ((u >> 16) & 1u)) >> 16;
    return (ushort)u;
}

__device__ __forceinline__ float fexp2(float x) {
#if __has_builtin(__builtin_amdgcn_exp2f)
    return __builtin_amdgcn_exp2f(x);
#else
    return exp2f(x);
#endif
}

// packed f32x2 -> bf16x2 (lo = a, hi = b); no builtin on gfx950, inline asm
__device__ __forceinline__ uint cvt_pk_bf16(float a, float b) {
    uint r;
    asm("v_cvt_pk_bf16_f32 %0, %1, %2" : "=v"(r) : "v"(a), "v"(b));
    return r;
}

// async global->LDS 16B: lane i lands at lds + i*16 (wave-uniform lds base)
__device__ __forceinline__ void gload16(const ushort* g, ushort* l, int lane) {
#if __has_builtin(__builtin_amdgcn_global_load_lds)
    __builtin_amdgcn_global_load_lds(
        (const __attribute__((address_space(1))) uint*)g,
        (__attribute__((address_space(3))) uint*)l, 16, 0, 0);
#else
    *(uint4*)(l + (size_t)lane * 8) = *(const uint4*)g;
#endif
}

// ---------------------------------------------------------------------------
// ALL weight conversions in one dispatch:
//   [0, 663552)        in_w   -> Wb
//   [663552, 884736)   out_w
//   [884736, 1769472)  w1
//   [1769472, 2654208) w2  (k-columns kappa-permuted: k ^= 12 when bit2^bit3,
//                           matching fused_mlp's register-transposed H slots)
//   [2654208, 2801664) conv_w (transposed to [co][kh*192+c])
__global__ __launch_bounds__(256) void cvt_weights(const float* __restrict__ in_w,
                                                   const float* __restrict__ out_w,
                                                   const float* __restrict__ w1,
                                                   const float* __restrict__ w2,
                                                   const float* __restrict__ convw,
                                                   ushort* __restrict__ Wb) {
    int t = blockIdx.x * 256 + threadIdx.x;
    if (t >= 2801664) return;
    float v;
    if (t < 663552)        v = in_w[t];
    else if (t < 884736)   v = out_w[t - 663552];
    else if (t < 1769472)  v = w1[t - 884736];
    else if (t < 2654208) {
        int u = t - 1769472;
        int k = u % 768;
        int ks = k ^ ((((k >> 2) ^ (k >> 3)) & 1) * 12);
        v = w2[u - k + ks];
    } else {
        int u = t - 2654208;
        int co = u / 576, rem = u % 576;
        int kh = rem / Ed, c = rem % Ed;
        v = convw[((size_t)co * Ed + c) * 3 + kh];
    }
    Wb[t] = f2b(v);
}

// ---------------------------------------------------------------------------
// FUSED reshape + layer-0 LN1: image [B,E,8,64] -> LN over E at rows
// s = w*8 + h -> F1 fp32 + XNb bf16.
__global__ __launch_bounds__(256) void reshape_ln(const float* __restrict__ img,
                                                  const float* __restrict__ g,
                                                  const float* __restrict__ bb,
                                                  float* __restrict__ outf,
                                                  ushort* __restrict__ outb) {
    __shared__ float lds[Ed * 65];               // 49920 B
    const int b = blockIdx.x >> 3, h = blockIdx.x & 7;
    const int tid = threadIdx.x;
    const float* src = img + ((size_t)b * Ed * Himg + h) * Wimg;  // +c*512+w
    #pragma unroll
    for (int i = 0; i < 48; ++i) {
        int idx = i * 256 + tid;
        int c = idx >> 6, w = idx & 63;
        lds[c * 65 + w] = src[(size_t)c * 512 + w];
    }
    __syncthreads();

    const int w = tid >> 2, q = tid & 3;         // 4 lanes per row w
    float vals[48];
    float s = 0.f;
    #pragma unroll
    for (int j = 0; j < 48; ++j) {
        vals[j] = lds[(q * 48 + j) * 65 + w];
        s += vals[j];
    }
    s += __shfl_xor(s, 1); s += __shfl_xor(s, 2);
    float mu = s * (1.f / 192.f);
    float qv = 0.f;
    #pragma unroll
    for (int j = 0; j < 48; ++j) { float d = vals[j] - mu; qv += d * d; }
    qv += __shfl_xor(qv, 1); qv += __shfl_xor(qv, 2);
    float rstd = rsqrtf(qv * (1.f / 192.f) + 1e-5f);

    size_t row = (size_t)b * Ssz + w * Himg + h;
    float*  of = outf + row * Ed + q * 48;
    ushort* ob = outb + row * Ed + q * 48;
    const float* gg = g + q * 48;
    const float* bv = bb + q * 48;
    #pragma unroll
    for (int j = 0; j < 48; ++j) {
        float y = (vals[j] - mu) * rstd * gg[j] + bv[j];
        of[j] = y;
        ob[j] = f2b(y);
    }
}

// ---------------------------------------------------------------------------
// bf16 MFMA GEMM: BM=128 BN=64 BK=96; 256 thr / 4 waves.
// VOUT: Q cols -> QP[bh][s][32] (pre-scaled by log2(e)/sqrt(hd)),
//       K cols -> KP[bh][s][32], V cols -> VT[bh][d][s'] (kappa order).
template<int RELU, int RESID, int OBF, int VOUT>
__global__ __launch_bounds__(256) void gemm_mfma(
    const ushort* __restrict__ A, const ushort* __restrict__ Wt,
    const float* __restrict__ bias, const float* __restrict__ resid,
    float* __restrict__ C, ushort* __restrict__ Cb,
    ushort* __restrict__ qpout, ushort* __restrict__ kpout,
    ushort* __restrict__ vtout,
    int M, int N, int K)
{
    __shared__ __align__(16) ushort As[12288];   // 24 frags (8 msub x 3 ksub) * 1KB
    __shared__ __align__(16) ushort Bs[6144];    // 12 frags (4 nsub x 3 ksub) * 1KB
    const int tid  = threadIdx.x;
    const int lane = tid & 63;
    const int wave = tid >> 6;
    const int wr = wave >> 1, wc = wave & 1;
    const int bm = blockIdx.x * 128;
    const int bn = blockIdx.y * 64;

    const ushort* Ag[6]; ushort* Al[6];
    #pragma unroll
    for (int i = 0; i < 6; ++i) {
        int fa = 4 * i + wave;                 // 0..23
        int msub = fa / 3, ksub = fa % 3;
        int m = msub * 16 + (lane & 15);
        int k = ksub * 32 + ((lane >> 4) << 3);
        Ag[i] = A + (size_t)(bm + m) * K + k;
        Al[i] = As + fa * 512;                 // wave-uniform
    }
    const ushort* Bg[3]; ushort* Bl[3];
    #pragma unroll
    for (int i = 0; i < 3; ++i) {
        int fb = 4 * i + wave;                 // 0..11
        int nsub = fb / 3, ksub = fb % 3;
        int n = nsub * 16 + (lane & 15);
        int k = ksub * 32 + ((lane >> 4) << 3);
        Bg[i] = Wt + (size_t)(bn + n) * K + k;
        Bl[i] = Bs + fb * 512;
    }

    f32x4 acc[4][2];
    #pragma unroll
    for (int i = 0; i < 4; ++i)
        #pragma unroll
        for (int j = 0; j < 2; ++j) acc[i][j] = (f32x4){0.f, 0.f, 0.f, 0.f};

    for (int k0 = 0; k0 < K; k0 += 96) {
        #pragma unroll
        for (int i = 0; i < 6; ++i) gload16(Ag[i] + k0, Al[i], lane);
        #pragma unroll
        for (int i = 0; i < 3; ++i) gload16(Bg[i] + k0, Bl[i], lane);
        __syncthreads();
        #pragma unroll
        for (int ksub = 0; ksub < 3; ++ksub) {
            short8 af[4], bf[2];
            #pragma unroll
            for (int ms = 0; ms < 4; ++ms)
                af[ms] = *(const short8*)(As + (((wr*4+ms)*3 + ksub) * 64 + lane) * 8);
            #pragma unroll
            for (int ns = 0; ns < 2; ++ns)
                bf[ns] = *(const short8*)(Bs + (((wc*2+ns)*3 + ksub) * 64 + lane) * 8);
            #pragma unroll
            for (int ms = 0; ms < 4; ++ms)
                #pragma unroll
                for (int ns = 0; ns < 2; ++ns)
                    acc[ms][ns] = __builtin_amdgcn_mfma_f32_16x16x32_bf16(
                        af[ms], bf[ns], acc[ms][ns], 0, 0, 0);
        }
        __syncthreads();
    }

    int q = lane >> 4, colL = lane & 15;
    #pragma unroll
    for (int ms = 0; ms < 4; ++ms) {
        #pragma unroll
        for (int ns = 0; ns < 2; ++ns) {
            int row0 = bm + (wr*4 + ms) * 16 + q * 4;
            int col  = bn + (wc*2 + ns) * 16 + colL;
            float bvv = bias[col];
            float v[4];
            #pragma unroll
            for (int r = 0; r < 4; ++r) {
                v[r] = acc[ms][ns][r] + bvv;
                if (RELU) v[r] = fmaxf(v[r], 0.f);
                if (RESID) v[r] += resid[(size_t)(row0 + r) * N + col];
            }
            if (VOUT) {
                int bidx = row0 >> 9, srow = row0 & 511;
                if (col >= 384) {                 // V -> VT[bh][d][s'] (kappa)
                    int hh = (col - 384) >> 5, dd = (col - 384) & 31;
                    int sr = srow ^ ((((srow >> 2) ^ (srow >> 3)) & 1) * 12);
                    ushort4 pv;
                    pv.x = f2b(v[0]); pv.y = f2b(v[1]); pv.z = f2b(v[2]); pv.w = f2b(v[3]);
                    *(ushort4*)(vtout + (((size_t)(bidx * NHd + hh) * 32 + dd) << 9) + sr) = pv;
                } else {                          // Q/K -> {QP,KP}[bh][s][32]
                    ushort* dst = (col < 192) ? qpout : kpout;
                    int cc = (col < 192) ? col : col - 192;
                    if (col < 192) {              // fold log2(e)/sqrt(32) into Q
                        const float c2 = 0.2550547270628364f;
                        #pragma unroll
                        for (int r = 0; r < 4; ++r) v[r] *= c2;
                    }
                    int hh = cc >> 5, dd = cc & 31;
                    ushort* p = dst + ((size_t)(bidx * NHd + hh) << 14) + (size_t)srow * 32 + dd;
                    p[0]  = f2b(v[0]); p[32] = f2b(v[1]);
                    p[64] = f2b(v[2]); p[96] = f2b(v[3]);
                }
            } else {
                #pragma unroll
                for (int r = 0; r < 4; ++r) {
                    if (OBF) Cb[(size_t)(row0 + r) * N + col] = f2b(v[r]);
                    else     C [(size_t)(row0 + r) * N + col] = v[r];
                }
            }
        }
    }
}

// ---------------------------------------------------------------------------
// Fused GEMM (+bias +resid) + row-LN. N=192 fixed. Used for out-proj only.
// BM=64, BN=192, BK=64, 256 thr / 4 waves. K = KIT*64.
template<int KIT>
__global__ __launch_bounds__(256) void gemm_ln(
    const ushort* __restrict__ A, const ushort* __restrict__ Wt,
    const float* __restrict__ bias, const float* __restrict__ resid,
    const float* __restrict__ lng, const float* __restrict__ lnb,
    float* __restrict__ outf, ushort* __restrict__ outb)
{
    __shared__ __align__(16) ushort As[4096];    // 8 frags (4 msub x 2 ksub)
    __shared__ __align__(16) ushort Bs[12288];   // 24 frags (12 nsub x 2 ksub)
    const int K = KIT * 64;
    const int lane = threadIdx.x & 63;
    const int wave = threadIdx.x >> 6;
    const int g = lane >> 4, ql = lane & 15;
    const int bm = blockIdx.x * 64;

    const ushort* Gp[8]; ushort* Lp[8];
    #pragma unroll
    for (int i = 0; i < 8; ++i) {
        int f = 4 * i + wave;                    // 0..31
        if (f < 8) {
            int msub = f >> 1, ksub = f & 1;
            Gp[i] = A + (size_t)(bm + msub * 16 + ql) * K + ksub * 32 + g * 8;
            Lp[i] = As + f * 512;
        } else {
            int fb = f - 8, nsub = fb >> 1, ksub = fb & 1;
            Gp[i] = Wt + (size_t)(nsub * 16 + ql) * K + ksub * 32 + g * 8;
            Lp[i] = Bs + fb * 512;
        }
    }

    f32x4 acc[12];
    #pragma unroll
    for (int i = 0; i < 12; ++i) acc[i] = (f32x4){0.f, 0.f, 0.f, 0.f};

    for (int kc = 0; kc < KIT; ++kc) {
        #pragma unroll
        for (int i = 0; i < 8; ++i) gload16(Gp[i] + kc * 64, Lp[i], lane);
        __syncthreads();
        #pragma unroll
        for (int ksub = 0; ksub < 2; ++ksub) {
            short8 af = *(const short8*)(As + ((wave * 2 + ksub) * 64 + lane) * 8);
            #pragma unroll
            for (int ns = 0; ns < 12; ++ns) {
                short8 bf = *(const short8*)(Bs + ((ns * 2 + ksub) * 64 + lane) * 8);
                acc[ns] = __builtin_amdgcn_mfma_f32_16x16x32_bf16(af, bf, acc[ns], 0, 0, 0);
            }
        }
        __syncthreads();
    }

    float bi[12], gg[12], bb[12];
    #pragma unroll
    for (int ns = 0; ns < 12; ++ns) {
        int col = ns * 16 + ql;
        bi[ns] = bias[col];
        gg[ns] = lng[col]; bb[ns] = lnb[col];
    }
    #pragma unroll
    for (int r = 0; r < 4; ++r) {
        int row = bm + wave * 16 + g * 4 + r;
        float v[12];
        #pragma unroll
        for (int ns = 0; ns < 12; ++ns)
            v[ns] = acc[ns][r] + bi[ns] + resid[(size_t)row * Ed + ns * 16 + ql];
        float s = 0.f;
        #pragma unroll
        for (int ns = 0; ns < 12; ++ns) s += v[ns];
        s += __shfl_xor(s, 1); s += __shfl_xor(s, 2);
        s += __shfl_xor(s, 4); s += __shfl_xor(s, 8);
        float mu = s * (1.f / 192.f);
        float qv = 0.f;
        #pragma unroll
        for (int ns = 0; ns < 12; ++ns) { float d = v[ns] - mu; qv += d * d; }
        qv += __shfl_xor(qv, 1); qv += __shfl_xor(qv, 2);
        qv += __shfl_xor(qv, 4); qv += __shfl_xor(qv, 8);
        float rstd = rsqrtf(qv * (1.f / 192.f) + 1e-5f);
        #pragma unroll
        for (int ns = 0; ns < 12; ++ns) {
            float y = (v[ns] - mu) * rstd * gg[ns] + bb[ns];
            int col = ns * 16 + ql;
            outf[(size_t)row * Ed + col] = y;
            outb[(size_t)row * Ed + col] = f2b(y);
        }
    }
}

// ---------------------------------------------------------------------------
// FUSED MLP v5: Y = relu(X@W1^T + b1)@W2k^T + b2 + resid, then epilogue.
// v2-v4 plateau ~50-56 us with per-iteration cost ~5000cy >> per-wave
// compute (~500cy) -> hypothesis: the cost is PER-BARRIER (vmcnt0+lgkm0
// drain, 24 of them, 1 block/CU so nothing fills the drain). v5 halves the
// barrier count: 64-H-column chunks, 12 iterations, 3 LDS buffers of 48 KB
// (144 KB, still 1 block/CU), v4's pipelined schedule: per iter
// STAGE(c+2) -> P1(c+1) [24 MFMA, halves a+b] -> PACKa/P2a -> PACKb/P2b.
// Each wave stages 6 of 48 frags. kappa (k^12, within 16-groups) is
// consistent per 32-col half. MODE=1: LN epilogue. MODE=2: im2col scatter.
template<int MODE>
__global__ __launch_bounds__(512) void fused_mlp(
    const ushort* __restrict__ X, const ushort* __restrict__ W1,
    const float* __restrict__ b1, const ushort* __restrict__ W2k,
    const float* __restrict__ b2, const float* __restrict__ resid,
    const float* __restrict__ lng, const float* __restrict__ lnb,
    float* __restrict__ outf, ushort* __restrict__ outb,
    ushort* __restrict__ a2out)
{
    __shared__ __align__(16) ushort Ws[3][48][512];   // 144 KB
    const int lane = threadIdx.x & 63;
    const int wave = threadIdx.x >> 6;           // 0..7
    const int g = lane >> 4, ql = lane & 15;
    const int bm = blockIdx.x * 128;
    const int row16 = bm + wave * 16;            // this wave's 16 rows
    const f32x4 z = {0.f,0.f,0.f,0.f};

    short8 xf[6];                                // X B-frags: row=ql, k=g*8
    #pragma unroll
    for (int ks = 0; ks < 6; ++ks)
        xf[ks] = *(const short8*)(X + (size_t)(row16 + ql) * Ed + ks * 32 + g * 8);

    // staging: 6 frags per wave: f = wave*6 + i.
    // f<24:  W1 frag (hsub=f/6 in 0..3 -> rows 16*hsub of the 64-row chunk,
    //        ksub=f%6), chunk stride 64*Ed.
    // f>=24: W2 frag (n2=(f-24)>>1, kk=(f-24)&1 -> k-half), chunk stride 64.
    const ushort* gsrc[6]; ushort* ldst[6]; int strd[6];
    #pragma unroll
    for (int i = 0; i < 6; ++i) {
        int f = wave * 6 + i;
        if (f < 24) {
            int hsub = f / 6, ksub = f % 6;
            gsrc[i] = W1 + (size_t)(hsub * 16 + ql) * Ed + ksub * 32 + g * 8;
            strd[i] = 64 * Ed;
        } else {
            int n2 = (f - 24) >> 1, kk = (f - 24) & 1;
            gsrc[i] = W2k + (size_t)(n2 * 16 + ql) * 768 + kk * 32 + g * 8;
            strd[i] = 64;
        }
        ldst[i] = &Ws[0][f][0];
    }
    auto STAGE = [&](int c) {
        int b = c % 3;
        #pragma unroll
        for (int i = 0; i < 6; ++i)
            gload16(gsrc[i] + (size_t)c * strd[i], ldst[i] + b * 24576, lane);
    };

    f32x4 yacc[12];
    #pragma unroll
    for (int i = 0; i < 12; ++i) yacc[i] = z;

    f32x4 st_[2][4];                             // [chunk parity][a0,a1,b0,b1]

    auto P1 = [&](int c) {                       // 24 MFMAs -> st_[c&1]
        const ushort* wb = &Ws[c % 3][0][0];
        f32x4 a0 = z, a1 = z, b0 = z, b1v = z;
        #pragma unroll
        for (int ks = 0; ks < 6; ++ks) {
            short8 w0 = *(const short8*)(wb + (size_t)ks * 512 + lane * 8);
            short8 w1f = *(const short8*)(wb + (size_t)(6 + ks) * 512 + lane * 8);
            short8 w2f = *(const short8*)(wb + (size_t)(12 + ks) * 512 + lane * 8);
            short8 w3f = *(const short8*)(wb + (size_t)(18 + ks) * 512 + lane * 8);
            a0  = __builtin_amdgcn_mfma_f32_16x16x32_bf16(w0,  xf[ks], a0, 0, 0, 0);
            a1  = __builtin_amdgcn_mfma_f32_16x16x32_bf16(w1f, xf[ks], a1, 0, 0, 0);
            b0  = __builtin_amdgcn_mfma_f32_16x16x32_bf16(w2f, xf[ks], b0, 0, 0, 0);
            b1v = __builtin_amdgcn_mfma_f32_16x16x32_bf16(w3f, xf[ks], b1v, 0, 0, 0);
        }
        st_[c & 1][0] = a0; st_[c & 1][1] = a1;
        st_[c & 1][2] = b0; st_[c & 1][3] = b1v;
    };
    auto PACK = [&](int c, int half) -> short8 { // bias+relu+pack+transpose
        float4 bA = *(const float4*)(b1 + c * 64 + half * 32 + 4 * g);
        float4 bB = *(const float4*)(b1 + c * 64 + half * 32 + 16 + 4 * g);
        const f32x4 s0 = st_[c & 1][half * 2], s1 = st_[c & 1][half * 2 + 1];
        float p8[8];
        p8[0] = fmaxf(s0[0] + bA.x, 0.f);
        p8[1] = fmaxf(s0[1] + bA.y, 0.f);
        p8[2] = fmaxf(s0[2] + bA.z, 0.f);
        p8[3] = fmaxf(s0[3] + bA.w, 0.f);
        p8[4] = fmaxf(s1[0] + bB.x, 0.f);
        p8[5] = fmaxf(s1[1] + bB.y, 0.f);
        p8[6] = fmaxf(s1[2] + bB.z, 0.f);
        p8[7] = fmaxf(s1[3] + bB.w, 0.f);
        uint Au = cvt_pk_bf16(p8[0], p8[1]);
        uint Bu = cvt_pk_bf16(p8[2], p8[3]);
        uint Cu = cvt_pk_bf16(p8[4], p8[5]);
        uint Du = cvt_pk_bf16(p8[6], p8[7]);
        asm("v_permlane32_swap_b32 %0, %1" : "+v"(Au), "+v"(Cu));
        asm("v_permlane32_swap_b32 %0, %1" : "+v"(Bu), "+v"(Du));
        union { uint u[4]; short8 s; } pk;
        pk.u[0] = Au; pk.u[1] = Bu; pk.u[2] = Cu; pk.u[3] = Du;
        return pk.s;                             // H A-frag, kappa slot order
    };
    auto P2 = [&](int c, int half, short8 pa) {  // 12 MFMAs -> yacc
        const ushort* wb = &Ws[c % 3][0][0];
        #pragma unroll
        for (int n2 = 0; n2 < 12; ++n2) {
            short8 bfr = *(const short8*)(wb + (size_t)(24 + n2 * 2 + half) * 512 + lane * 8);
            yacc[n2] = __builtin_amdgcn_mfma_f32_16x16x32_bf16(pa, bfr, yacc[n2], 0, 0, 0);
        }
    };

    STAGE(0); STAGE(1);
    __syncthreads();                             // buf0, buf1 ready
    P1(0);
    #pragma unroll
    for (int c = 0; c < 12; ++c) {
        if (c > 0) __syncthreads();              // buf c+1 ready; buf (c+2)%3 free
        if (c < 10) STAGE(c + 2);
        if (c < 11) P1(c + 1);
        short8 paA = PACK(c, 0);
        __builtin_amdgcn_s_setprio(1);
        P2(c, 0, paA);
        __builtin_amdgcn_s_setprio(0);
        short8 paB = PACK(c, 1);
        __builtin_amdgcn_s_setprio(1);
        P2(c, 1, paB);
        __builtin_amdgcn_s_setprio(0);
    }

    // epilogue (gemm_ln layout: row = row16 + g*4 + r, col = ns*16 + ql)
    float bi[12], gg[12], bb[12];
    #pragma unroll
    for (int ns = 0; ns < 12; ++ns) {
        int col = ns * 16 + ql;
        bi[ns] = b2[col];
        if (MODE == 1) { gg[ns] = lng[col]; bb[ns] = lnb[col]; }
    }
    #pragma unroll
    for (int r = 0; r < 4; ++r) {
        int row = row16 + g * 4 + r;
        float v[12];
        #pragma unroll
        for (int ns = 0; ns < 12; ++ns)
            v[ns] = yacc[ns][r] + bi[ns] + resid[(size_t)row * Ed + ns * 16 + ql];
        if (MODE == 1) {
            float s = 0.f;
            #pragma unroll
            for (int ns = 0; ns < 12; ++ns) s += v[ns];
            s += __shfl_xor(s, 1); s += __shfl_xor(s, 2);
            s += __shfl_xor(s, 4); s += __shfl_xor(s, 8);
            float mu = s * (1.f / 192.f);
            float qv = 0.f;
            #pragma unroll
            for (int ns = 0; ns < 12; ++ns) { float d = v[ns] - mu; qv += d * d; }
            qv += __shfl_xor(qv, 1); qv += __shfl_xor(qv, 2);
            qv += __shfl_xor(qv, 4); qv += __shfl_xor(qv, 8);
            float rstd = rsqrtf(qv * (1.f / 192.f) + 1e-5f);
            #pragma unroll
            for (int ns = 0; ns < 12; ++ns) {
                float y = (v[ns] - mu) * rstd * gg[ns] + bb[ns];
                int col = ns * 16 + ql;
                outf[(size_t)row * Ed + col] = y;
                outb[(size_t)row * Ed + col] = f2b(y);
            }
        } else {
            int bz = row >> 9, s = row & 511;
            int w = s >> 3, h = s & 7;
            #pragma unroll
            for (int ho = 0; ho < 4; ++ho) {
                int kh = h + 1 - 2 * ho;
                if (kh >= 0 && kh < 3) {
                    size_t r2 = ((size_t)((bz * 4 + ho) * 64 + w)) * 576 + kh * 192;
                    #pragma unroll
                    for (int ns = 0; ns < 12; ++ns)
                        a2out[r2 + ns * 16 + ql] = f2b(v[ns]);
                }
            }
            if (h == 0) {                       // top pad: hin = -1 stripe
                size_t r2 = ((size_t)(bz * 4 * 64 + w)) * 576;   // ho=0, kh=0
                #pragma unroll
                for (int ns = 0; ns < 12; ++ns)
                    a2out[r2 + ns * 16 + ql] = 0;
            }
        }
    }
}

// ---------------------------------------------------------------------------
// MFMA attention (round-5 best: 41.3 us), 2 q-tiles per wave (32 q x 512
// keys), LDS-free with in-register P transpose. Score stage pipelined one
// tile deep; K 3-deep, V 2-deep prefetch. grid (384 bh, 4); 4 waves.
template<int USE_MASK>
__global__ __launch_bounds__(256) void attn_mfma(const ushort* __restrict__ qp,
                                                 const ushort* __restrict__ kp,
                                                 const ushort* __restrict__ vt,
                                                 ushort* __restrict__ att) {
    const int bh = blockIdx.x;
    const int b = bh / NHd, h = bh % NHd;
    const int wave = threadIdx.x >> 6, lane = threadIdx.x & 63;
    const int g = lane >> 4, ql = lane & 15;
    const int qb = blockIdx.y * 128 + wave * 32;

    const ushort* qbase = qp + ((size_t)bh << 14);
    const ushort* kbase = kp + ((size_t)bh << 14);
    const ushort* vbase = vt + ((size_t)bh << 14);
    short8 qf[2];
    #pragma unroll
    for (int t = 0; t < 2; ++t)
        qf[t] = *(const short8*)(qbase + (size_t)(qb + t * 16 + ql) * 32 + g * 8);

    short8 onesf;
    #pragma unroll
    for (int j = 0; j < 8; ++j) onesf[j] = (short)0x3F80;   // bf16 1.0

    uint m0[2], m1[2]; int qh[2];
    if (USE_MASK) {
        #pragma unroll
        for (int t = 0; t < 2; ++t) {
            int qwt = ((qb + t * 16) & 63) + ql;      // no wrap: base%16==0
            qh[t] = (qb + t * 16) >> 6;
            uint a0 = 0, a1 = 0;
            #pragma unroll
            for (int i = 0; i < 8; ++i) {
                int keyl = (i >> 2) * 16 + 4 * g + (i & 3);
                int d0 = keyl - qwt;      d0 = d0 < 0 ? -d0 : d0;
                int d1 = keyl + 32 - qwt; d1 = d1 < 0 ? -d1 : d1;
                if (d0 <= 5) a0 |= (1u << i);
                if (d1 <= 5) a1 |= (1u << i);
            }
            m0[t] = a0; m1[t] = a1;
        }
    }

    f32x4 o0[2], o1[2], o2[2];
    #pragma unroll
    for (int t = 0; t < 2; ++t) {
        o0[t] = (f32x4){0.f,0.f,0.f,0.f};
        o1[t] = (f32x4){0.f,0.f,0.f,0.f};
        o2[t] = (f32x4){0.f,0.f,0.f,0.f};
    }
    const f32x4 z = {0.f,0.f,0.f,0.f};

    short8 kb_[3][2];     // K tiles, 3-deep rotation
    short8 vb_[2][2];     // V tiles, 2-deep rotation
    f32x4  st_[2][4];     // scores in flight, 2 tiles: [parity][t*2+half]
    short8 pa[2];         // transposed P A-frags for current tile

    auto LK = [&](int kt, short8* d) {
        d[0] = *(const short8*)(kbase + (size_t)(kt * 32 + ql) * 32 + g * 8);
        d[1] = *(const short8*)(kbase + (size_t)(kt * 32 + 16 + ql) * 32 + g * 8);
    };
    auto LV = [&](int kt, short8* d) {
        d[0] = *(const short8*)(vbase + (size_t)ql * 512 + kt * 32 + 8 * g);
        d[1] = *(const short8*)(vbase + (size_t)(16 + ql) * 512 + kt * 32 + 8 * g);
    };
    auto S = [&](const short8* k, f32x4* st) {    // 4 score MFMAs
        st[0] = __builtin_amdgcn_mfma_f32_16x16x32_bf16(k[0], qf[0], z, 0, 0, 0);
        st[1] = __builtin_amdgcn_mfma_f32_16x16x32_bf16(k[1], qf[0], z, 0, 0, 0);
        st[2] = __builtin_amdgcn_mfma_f32_16x16x32_bf16(k[0], qf[1], z, 0, 0, 0);
        st[3] = __builtin_amdgcn_mfma_f32_16x16x32_bf16(k[1], qf[1], z, 0, 0, 0);
    };
    auto F = [&](int kt, const f32x4* st) {       // exp2+mask+pack+transpose
        #pragma unroll
        for (int t = 0; t < 2; ++t) {
            float p8[8];
            #pragma unroll
            for (int r = 0; r < 4; ++r) {
                p8[r]     = fexp2(st[t*2][r]);
                p8[4 + r] = fexp2(st[t*2+1][r]);
            }
            if (USE_MASK) {
                int dh = (kt >> 1) - qh[t]; dh = dh < 0 ? -dh : dh;
                if (dh <= 3) {
                    uint mm = (kt & 1) ? m1[t] : m0[t];
                    #pragma unroll
                    for (int i = 0; i < 8; ++i)
                        if ((mm >> i) & 1u) p8[i] = 0.f;
                }
            }
            uint Au = cvt_pk_bf16(p8[0], p8[1]);   // keys 4g+0,4g+1
            uint Bu = cvt_pk_bf16(p8[2], p8[3]);   // keys 4g+2,4g+3
            uint Cu = cvt_pk_bf16(p8[4], p8[5]);   // keys 16+4g+0,+1
            uint Du = cvt_pk_bf16(p8[6], p8[7]);   // keys 16+4g+2,+3
            asm("v_permlane32_swap_b32 %0, %1" : "+v"(Au), "+v"(Cu));
            asm("v_permlane32_swap_b32 %0, %1" : "+v"(Bu), "+v"(Du));
            union { uint u[4]; short8 s; } pk;
            pk.u[0] = Au; pk.u[1] = Bu; pk.u[2] = Cu; pk.u[3] = Du;
            pa[t] = pk.s;                           // A-frag in kappa key-order
        }
    };
    auto PV = [&](const short8* v) {
        #pragma unroll
        for (int t = 0; t < 2; ++t) {
            o0[t] = __builtin_amdgcn_mfma_f32_16x16x32_bf16(pa[t], v[0], o0[t], 0, 0, 0);
            o1[t] = __builtin_amdgcn_mfma_f32_16x16x32_bf16(pa[t], v[1], o1[t], 0, 0, 0);
            o2[t] = __builtin_amdgcn_mfma_f32_16x16x32_bf16(pa[t], onesf, o2[t], 0, 0, 0);
        }
    };

    // --- pipelined loop over 16 key-tiles ----------------------------------
    LK(0, kb_[0]); LK(1, kb_[1]); LK(2, kb_[2]);
    LV(0, vb_[0]); LV(1, vb_[1]);
    S(kb_[0], st_[0]);
    #pragma unroll
    for (int kt = 0; kt < 16; ++kt) {
        if (kt < 15) S(kb_[(kt + 1) % 3], st_[(kt + 1) & 1]);  // next scores
        if (kt < 13) LK(kt + 3, kb_[kt % 3]);                  // K 3 ahead
        F(kt, st_[kt & 1]);                                    // finish cur
        __builtin_amdgcn_s_setprio(1);
        PV(vb_[kt & 1]);                                       // PV cur
        __builtin_amdgcn_s_setprio(0);
        if (kt < 14) LV(kt + 2, vb_[kt & 1]);                  // V 2 ahead
    }

    ushort* op = att + (size_t)b * Ssz * Ed + h * 32;
    #pragma unroll
    for (int t = 0; t < 2; ++t) {
        #pragma unroll
        for (int r = 0; r < 4; ++r) {
            float iv = 1.f / o2[t][r];
            int row = qb + t * 16 + 4 * g + r;
            op[(size_t)row * Ed + ql]      = f2b(o0[t][r] * iv);
            op[(size_t)row * Ed + 16 + ql] = f2b(o1[t][r] * iv);
        }
    }
}

// ---------------------------------------------------------------------------
// channel LN on conv output C2[r=(b*4+ho)*64+w][co=256] -> out[b,co,ho,w]
__global__ __launch_bounds__(256) void ln_out_kernel(const float* __restrict__ C2,
                                                     const float* __restrict__ g,
                                                     const float* __restrict__ beta,
                                                     float* __restrict__ out) {
    __shared__ float lds[32 * 257];
    int w0 = blockIdx.x * 32, ho = blockIdx.y, b = blockIdx.z;
    int tid = threadIdx.x;
    size_t rbase = ((size_t)b * 4 + ho) * 64 + w0;

    for (int i = 0; i < 32; ++i)
        lds[i * 257 + tid] = C2[(rbase + i) * COd + tid];
    __syncthreads();

    int wv = tid >> 6, lane = tid & 63;
    for (int rr = 0; rr < 8; ++rr) {
        int i = wv * 8 + rr;
        float v0 = lds[i*257 + lane], v1 = lds[i*257 + lane + 64];
        float v2 = lds[i*257 + lane + 128], v3 = lds[i*257 + lane + 192];
        float s = v0 + v1 + v2 + v3;
        #pragma unroll
        for (int off = 32; off > 0; off >>= 1) s += __shfl_xor(s, off);
        float mu = s * (1.f / 256.f);
        float d0 = v0-mu, d1 = v1-mu, d2 = v2-mu, d3 = v3-mu;
        float qv = d0*d0 + d1*d1 + d2*d2 + d3*d3;
        #pragma unroll
        for (int off = 32; off > 0; off >>= 1) qv += __shfl_xor(qv, off);
        float rstd = rsqrtf(qv * (1.f / 256.f) + 1e-5f);
        lds[i*257 + lane]       = d0 * rstd * g[lane]       + beta[lane];
        lds[i*257 + lane + 64]  = d1 * rstd * g[lane + 64]  + beta[lane + 64];
        lds[i*257 + lane + 128] = d2 * rstd * g[lane + 128] + beta[lane + 128];
        lds[i*257 + lane + 192] = d3 * rstd * g[lane + 192] + beta[lane + 192];
    }
    __syncthreads();

    int w = tid & 31, half = tid >> 5;
    for (int j = 0; j < 32; ++j) {
        int co = half + j * 8;
        out[(((size_t)b * COd + co) * 4 + ho) * Wimg + w0 + w] = lds[w * 257 + co];
    }
}

// ---------------------------------------------------------------------------
extern "C" void kernel_launch(void* const* d_in, const int* in_sizes, int n_in,
                              void* d_out, int out_size, void* d_ws, size_t ws_size,
                              hipStream_t stream) {
    const float* image = (const float*)d_in[0];
    const float* in_w  = (const float*)d_in[1];
    const float* in_b  = (const float*)d_in[2];
    const float* out_w = (const float*)d_in[3];
    const float* out_b = (const float*)d_in[4];
    const float* ln1_g = (const float*)d_in[5];
    const float* ln1_b = (const float*)d_in[6];
    const float* ln2_g = (const float*)d_in[7];
    const float* ln2_b = (const float*)d_in[8];
    const float* w1    = (const float*)d_in[9];
    const float* b1    = (const float*)d_in[10];
    const float* w2    = (const float*)d_in[11];
    const float* b2    = (const float*)d_in[12];
    const float* convw = (const float*)d_in[13];
    const float* convb = (const float*)d_in[14];
    const float* mln_g = (const float*)d_in[15];
    const float* mln_b = (const float*)d_in[16];
    float* out = (float*)d_out;
    float* ws  = (float*)d_ws;

    // ws layout (float units):
    //  F1 (x1 stream fp32)   [0, 6291456)
    //  F2 (x3 stream fp32)   [6291456, 12582912)
    //  BIG [12582912, 28311552):
    //       QP bf16 @BIG | KP @+3145728 | VT @+6291456
    //       C2 f32 @BIG+4718592 (conv path, end)
    //  XNb  bf16 @ BIG+12582912  [25165824, 28311552)
    //  A2b  bf16 @ ws+25165824 (aliases dead XNb+ATTb at conv time)
    //  ATTb bf16 [28311552, 31457280)
    //  Wb   bf16 [31457280, 32858112)
    float* F1   = ws;
    float* F2   = ws + 6291456;
    float* BIG  = ws + 12582912;
    ushort* QP   = (ushort*)BIG;
    ushort* KP   = (ushort*)(BIG + 3145728);
    ushort* VT   = (ushort*)(BIG + 6291456);
    float*  C2   = BIG + 4718592;
    ushort* XNb  = (ushort*)(BIG + 12582912);
    ushort* A2b  = (ushort*)(ws + 25165824);
    ushort* ATTb = (ushort*)(ws + 28311552);
    ushort* Wb   = (ushort*)(ws + 31457280);

    ushort* in_wb  = Wb;                    // 663552
    ushort* out_wb = Wb + 663552;           // 221184
    ushort* w1b    = Wb + 884736;           // 884736
    ushort* w2b    = Wb + 1769472;          // 884736 (kappa k-order)
    ushort* cwb    = Wb + 2654208;          // 147456

    cvt_weights<<<(2801664 + 255) / 256, 256, 0, stream>>>(
        in_w, out_w, w1, w2, convw, Wb);

    // fused reshape + layer-0 LN1: image -> F1 (x1 fp32) + XNb (x1 bf16)
    reshape_ln<<<Bn * Himg, 256, 0, stream>>>(image, ln1_g, ln1_b, F1, XNb);

    for (int i = 0; i < Ld; ++i) {
        gemm_mfma<0,0,1,1><<<dim3(Mrows/128, 9), 256, 0, stream>>>(
            XNb, in_wb + (size_t)i * 3*Ed*Ed, in_b + i * 3*Ed,
            nullptr, nullptr, nullptr, QP, KP, VT, Mrows, 3*Ed, Ed);
        if (i >= 2) attn_mfma<1><<<dim3(Bn * NHd, 4), 256, 0, stream>>>(QP, KP, VT, ATTb);
        else        attn_mfma<0><<<dim3(Bn * NHd, 4), 256, 0, stream>>>(QP, KP, VT, ATTb);
        // out-proj + x1 + LN2 -> F2 (x3 fp32) + XNb (x3 bf16)
        gemm_ln<3><<<Mrows/64, 256, 0, stream>>>(
            ATTb, out_wb + (size_t)i * Ed*Ed, out_b + i*Ed,
            F1, ln2_g + i*Ed, ln2_b + i*Ed, F2, XNb);
        // fused MLP (mlp1 + relu + mlp2 + resid + epilogue), H in registers
        if (i < Ld - 1) {
            fused_mlp<1><<<Mrows/128, 512, 0, stream>>>(
                XNb, w1b + (size_t)i * 4*Ed*Ed, b1 + i * 4*Ed,
                w2b + (size_t)i * 4*Ed*Ed, b2 + i*Ed, F2,
                ln1_g + (i+1)*Ed, ln1_b + (i+1)*Ed, F1, XNb, nullptr);
        } else {
            fused_mlp<2><<<Mrows/128, 512, 0, stream>>>(
                XNb, w1b + (size_t)i * 4*Ed*Ed, b1 + i * 4*Ed,
                w2b + (size_t)i * 4*Ed*Ed, b2 + i*Ed, F2,
                nullptr, nullptr, nullptr, nullptr, A2b);
        }
    }

    gemm_mfma<0,0,0,0><<<dim3(16384/128, 4), 256, 0, stream>>>(
        A2b, cwb, convb, nullptr, C2, nullptr, nullptr, nullptr, nullptr,
        16384, COd, 576);
    ln_out_kernel<<<dim3(2, 4, Bn), 256, 0, stream>>>(C2, mln_g, mln_b, out);
}